// Round 1
// baseline (588.556 us; speedup 1.0000x reference)
//
#include <hip/hip_runtime.h>
#include <stdint.h>

#define B_  4
#define S_  2048
#define E_  1024
#define H_  16
#define D_  64
#define NEGV -1e20f

typedef __bf16 bf16;
typedef __bf16 bf16x4 __attribute__((ext_vector_type(4)));
typedef __bf16 bf16x8 __attribute__((ext_vector_type(8)));
typedef float  f32x4 __attribute__((ext_vector_type(4)));

__device__ __forceinline__ f32x4 mfma16(bf16x8 a, bf16x8 b, f32x4 c) {
  return __builtin_amdgcn_mfma_f32_16x16x32_bf16(a, b, c, 0, 0, 0);
}

// XOR swizzle in halfword units within a 64-halfword (128 B) row
__device__ __forceinline__ int sw(int row, int idx) { return idx ^ ((row & 7) << 3); }

// ---------------- mask packing ----------------
__global__ void pack_mask_kernel(const int* __restrict__ mask, uint32_t* __restrict__ mbits) {
  int idx = blockIdx.x * 256 + threadIdx.x;   // 2048*64 words
  int q = idx >> 6, w = idx & 63;
  const int* p = mask + q * S_ + w * 32;
  uint32_t bits = 0;
#pragma unroll
  for (int j = 0; j < 32; j += 4) {
    int4 v = *(const int4*)(p + j);
    bits |= (v.x != 0 ? 1u : 0u) << (j + 0);
    bits |= (v.y != 0 ? 1u : 0u) << (j + 1);
    bits |= (v.z != 0 ? 1u : 0u) << (j + 2);
    bits |= (v.w != 0 ? 1u : 0u) << (j + 3);
  }
  mbits[idx] = bits;
}

__global__ void pack_pad_kernel(const int* __restrict__ pad, uint32_t* __restrict__ pbits) {
  int idx = threadIdx.x;                      // 4*64 words
  int b = idx >> 6, w = idx & 63;
  const int* p = pad + b * S_ + w * 32;
  uint32_t bits = 0;
#pragma unroll
  for (int j = 0; j < 32; j += 4) {
    int4 v = *(const int4*)(p + j);
    bits |= (v.x != 0 ? 1u : 0u) << (j + 0);
    bits |= (v.y != 0 ? 1u : 0u) << (j + 1);
    bits |= (v.z != 0 ? 1u : 0u) << (j + 2);
    bits |= (v.w != 0 ? 1u : 0u) << (j + 3);
  }
  pbits[idx] = bits;
}

// ---------------- GEMM: C = A @ W^T (A: [M][1024], W: [1024][1024] row-major) ----------------
struct GemmArgs { const void* A; const float* W; void* O; float scale; };

template<bool A_F32, bool OUT_F32>
__global__ __launch_bounds__(256, 2)
void gemm_bt(GemmArgs g0, GemmArgs g1, GemmArgs g2) {
  GemmArgs g = (blockIdx.z == 0) ? g0 : ((blockIdx.z == 1) ? g1 : g2);
  const int tid = threadIdx.x;
  const int l = tid & 63, wv = tid >> 6;
  const int lg = l >> 4, lr = l & 15;
  const int wr = wv >> 1, wc = wv & 1;
  const int brow = blockIdx.y * 128, bcol = blockIdx.x * 128;

  __shared__ bf16 As[128 * 64];
  __shared__ bf16 Bs[128 * 64];

  f32x4 acc[4][4] = {};

  for (int kt = 0; kt < E_ / 64; ++kt) {
    __syncthreads();
    // ---- stage A tile (128 x 64) ----
    if constexpr (A_F32) {
      const float* A = (const float*)g.A;
      int rb = tid >> 4, c4 = tid & 15;
#pragma unroll
      for (int i = 0; i < 8; ++i) {
        int row = rb + 16 * i;
        float4 v = *(const float4*)(A + (size_t)(brow + row) * E_ + kt * 64 + c4 * 4);
        bf16x4 hv; hv[0] = (bf16)v.x; hv[1] = (bf16)v.y; hv[2] = (bf16)v.z; hv[3] = (bf16)v.w;
        *(bf16x4*)&As[sw(row, row * 64 + c4 * 4)] = hv;
      }
    } else {
      const bf16* A = (const bf16*)g.A;
      int rb = tid >> 3, c8 = tid & 7;
#pragma unroll
      for (int i = 0; i < 4; ++i) {
        int row = rb + 32 * i;
        bf16x8 v = *(const bf16x8*)(A + (size_t)(brow + row) * E_ + kt * 64 + c8 * 8);
        *(bf16x8*)&As[sw(row, row * 64 + c8 * 8)] = v;
      }
    }
    // ---- stage B tile (W, always fp32) ----
    {
      int rb = tid >> 4, c4 = tid & 15;
#pragma unroll
      for (int i = 0; i < 8; ++i) {
        int row = rb + 16 * i;
        float4 v = *(const float4*)(g.W + (size_t)(bcol + row) * E_ + kt * 64 + c4 * 4);
        bf16x4 hv; hv[0] = (bf16)v.x; hv[1] = (bf16)v.y; hv[2] = (bf16)v.z; hv[3] = (bf16)v.w;
        *(bf16x4*)&Bs[sw(row, row * 64 + c4 * 4)] = hv;
      }
    }
    __syncthreads();
    // ---- compute ----
#pragma unroll
    for (int kk = 0; kk < 2; ++kk) {
      bf16x8 af[4], bfr[4];
#pragma unroll
      for (int ms = 0; ms < 4; ++ms) {
        int row = wr * 64 + ms * 16 + lr;
        af[ms] = *(const bf16x8*)&As[sw(row, row * 64 + kk * 32 + lg * 8)];
      }
#pragma unroll
      for (int ns = 0; ns < 4; ++ns) {
        int row = wc * 64 + ns * 16 + lr;
        bfr[ns] = *(const bf16x8*)&Bs[sw(row, row * 64 + kk * 32 + lg * 8)];
      }
#pragma unroll
      for (int ms = 0; ms < 4; ++ms)
#pragma unroll
        for (int ns = 0; ns < 4; ++ns)
          acc[ms][ns] = mfma16(af[ms], bfr[ns], acc[ms][ns]);
    }
  }
  // ---- epilogue ----
#pragma unroll
  for (int ms = 0; ms < 4; ++ms) {
#pragma unroll
    for (int ns = 0; ns < 4; ++ns) {
#pragma unroll
      for (int r = 0; r < 4; ++r) {
        int row = brow + wr * 64 + ms * 16 + lg * 4 + r;
        int col = bcol + wc * 64 + ns * 16 + lr;
        float v = acc[ms][ns][r] * g.scale;
        if constexpr (OUT_F32) ((float*)g.O)[(size_t)row * E_ + col] = v;
        else                   ((bf16*)g.O)[(size_t)row * E_ + col] = (bf16)v;
      }
    }
  }
}

// ---------------- V transpose: V[b,s,h,d] -> Vt[b,h,d,s] ----------------
__global__ __launch_bounds__(256, 2)
void transpose_v(const bf16* __restrict__ V, bf16* __restrict__ Vt) {
  int bh = blockIdx.y; int b = bh >> 4, h = bh & 15;
  int s0 = blockIdx.x * 64;
  int tid = threadIdx.x;
  __shared__ bf16 t[64][72];
  int rb = tid >> 3, seg = tid & 7;
#pragma unroll
  for (int i = 0; i < 2; ++i) {
    int row = rb + 32 * i;
    bf16x8 v = *(const bf16x8*)(V + (size_t)(b * S_ + s0 + row) * E_ + h * 64 + seg * 8);
#pragma unroll
    for (int j = 0; j < 8; ++j) t[row][seg * 8 + j] = v[j];
  }
  __syncthreads();
#pragma unroll
  for (int i = 0; i < 2; ++i) {
    int d = rb + 32 * i;
    bf16x8 v;
#pragma unroll
    for (int j = 0; j < 8; ++j) v[j] = t[seg * 8 + j][d];
    *(bf16x8*)(Vt + ((size_t)bh * 64 + d) * S_ + s0 + seg * 8) = v;
  }
}

// ---------------- flash attention ----------------
__global__ __launch_bounds__(256, 2)
void attn_kernel(const bf16* __restrict__ Q, const bf16* __restrict__ K,
                 const bf16* __restrict__ Vt, const uint32_t* __restrict__ mbits,
                 const uint32_t* __restrict__ pbits, bf16* __restrict__ alpha) {
  const int bh = blockIdx.y, b = bh >> 4, h = bh & 15;
  const int tid = threadIdx.x, wv = tid >> 6, l = tid & 63;
  const int lg = l >> 4, lr = l & 15;
  const int q0 = blockIdx.x * 64 + wv * 16;

  __shared__ bf16 Ks[64 * 64];      // [k-row][d], swizzled
  __shared__ bf16 Vs[64 * 64];      // [d][k], swizzled
  __shared__ bf16 Ps[4][16 * 64];   // per-wave P tile [q][k], swizzled

  bf16x8 qa[2];
#pragma unroll
  for (int kk = 0; kk < 2; ++kk)
    qa[kk] = *(const bf16x8*)(Q + (size_t)(b * S_ + q0 + lr) * E_ + h * 64 + kk * 32 + lg * 8);

  f32x4 o[4] = {};
  float m_run[4], l_run[4];
#pragma unroll
  for (int r = 0; r < 4; ++r) { m_run[r] = -__builtin_inff(); l_run[r] = 0.f; }

  for (int kt = 0; kt < S_ / 64; ++kt) {
    __syncthreads();
    {
      int rb = tid >> 3, seg = tid & 7;
#pragma unroll
      for (int i = 0; i < 2; ++i) {
        int row = rb + 32 * i;
        bf16x8 kv = *(const bf16x8*)(K + (size_t)(b * S_ + kt * 64 + row) * E_ + h * 64 + seg * 8);
        *(bf16x8*)&Ks[sw(row, row * 64 + seg * 8)] = kv;
        bf16x8 vv = *(const bf16x8*)(Vt + ((size_t)bh * 64 + row) * S_ + kt * 64 + seg * 8);
        *(bf16x8*)&Vs[sw(row, row * 64 + seg * 8)] = vv;
      }
    }
    __syncthreads();

    // ---- scores: 16q x 64k ----
    f32x4 sc[4];
#pragma unroll
    for (int sub = 0; sub < 4; ++sub) {
      f32x4 s = {};
#pragma unroll
      for (int kk = 0; kk < 2; ++kk) {
        int row = sub * 16 + lr;
        bf16x8 kb = *(const bf16x8*)&Ks[sw(row, row * 64 + kk * 32 + lg * 8)];
        s = mfma16(qa[kk], kb, s);
      }
      sc[sub] = s;
    }

    // ---- masks ----
    uint32_t mw[4][2];
#pragma unroll
    for (int r = 0; r < 4; ++r) {
      int qg = q0 + lg * 4 + r;
      mw[r][0] = mbits[qg * 64 + kt * 2 + 0] & pbits[b * 64 + kt * 2 + 0];
      mw[r][1] = mbits[qg * 64 + kt * 2 + 1] & pbits[b * 64 + kt * 2 + 1];
    }

    // ---- online softmax (rows = lg*4+r, cols across 16 lanes x 4 subtiles) ----
    float p[4][4];
#pragma unroll
    for (int r = 0; r < 4; ++r) {
      float vmax = -__builtin_inff();
#pragma unroll
      for (int sub = 0; sub < 4; ++sub) {
        uint32_t bit = (mw[r][sub >> 1] >> (((sub & 1) << 4) + lr)) & 1u;
        float s = bit ? sc[sub][r] : NEGV;
        sc[sub][r] = s;
        vmax = fmaxf(vmax, s);
      }
#pragma unroll
      for (int off = 1; off < 16; off <<= 1) vmax = fmaxf(vmax, __shfl_xor(vmax, off));
      float mnew = fmaxf(m_run[r], vmax);
      float scale = __expf(m_run[r] - mnew);
      m_run[r] = mnew;
      float psum = 0.f;
#pragma unroll
      for (int sub = 0; sub < 4; ++sub) {
        float pv = (sc[sub][r] <= 0.5f * NEGV) ? 0.f : __expf(sc[sub][r] - mnew);
        p[sub][r] = pv;
        psum += pv;
      }
#pragma unroll
      for (int off = 1; off < 16; off <<= 1) psum += __shfl_xor(psum, off);
      l_run[r] = l_run[r] * scale + psum;
#pragma unroll
      for (int ds = 0; ds < 4; ++ds) o[ds][r] *= scale;
    }

    // ---- P -> LDS (per-wave, no barrier needed) ----
#pragma unroll
    for (int sub = 0; sub < 4; ++sub)
#pragma unroll
      for (int r = 0; r < 4; ++r) {
        int row = lg * 4 + r;
        Ps[wv][sw(row, row * 64 + sub * 16 + lr)] = (bf16)p[sub][r];
      }

    // ---- PV ----
#pragma unroll
    for (int kc = 0; kc < 2; ++kc) {
      bf16x8 pa = *(const bf16x8*)&Ps[wv][sw(lr, lr * 64 + kc * 32 + lg * 8)];
#pragma unroll
      for (int ds = 0; ds < 4; ++ds) {
        int row = ds * 16 + lr;
        bf16x8 vb = *(const bf16x8*)&Vs[sw(row, row * 64 + kc * 32 + lg * 8)];
        o[ds] = mfma16(pa, vb, o[ds]);
      }
    }
  }

  // ---- epilogue: alpha = o / l ----
#pragma unroll
  for (int r = 0; r < 4; ++r) {
    float inv = 1.0f / l_run[r];
#pragma unroll
    for (int ds = 0; ds < 4; ++ds) {
      int row = q0 + lg * 4 + r;
      int col = h * 64 + ds * 16 + lr;
      alpha[(size_t)(b * S_ + row) * E_ + col] = (bf16)(o[ds][r] * inv);
    }
  }
}

// ---------------- launch ----------------
extern "C" void kernel_launch(void* const* d_in, const int* in_sizes, int n_in,
                              void* d_out, int out_size, void* d_ws, size_t ws_size,
                              hipStream_t stream) {
  const float* query = (const float*)d_in[0];
  const float* key_t = (const float*)d_in[1];
  const float* value = (const float*)d_in[2];
  const int*   mask  = (const int*)d_in[3];
  const int*   pad   = (const int*)d_in[4];
  const float* Wq    = (const float*)d_in[5];
  const float* Wk    = (const float*)d_in[6];
  const float* Wv    = (const float*)d_in[7];
  const float* Wo    = (const float*)d_in[8];

  char* ws = (char*)d_ws;
  bf16* Qb = (bf16*)(ws);
  bf16* Kb = (bf16*)(ws + ((size_t)16 << 20));
  bf16* Vb = (bf16*)(ws + ((size_t)32 << 20));
  bf16* Vt = (bf16*)(ws + ((size_t)48 << 20));
  uint32_t* mbits = (uint32_t*)(ws + ((size_t)64 << 20));
  uint32_t* pbits = (uint32_t*)(ws + ((size_t)64 << 20) + (1 << 20));
  bf16* alpha = Vb;  // reuse: transpose consumes Vb before attn writes alpha

  pack_mask_kernel<<<512, 256, 0, stream>>>(mask, mbits);
  pack_pad_kernel<<<1, 256, 0, stream>>>(pad, pbits);

  const float qscale = 0.17677669529663687f;  // 1024^-0.25
  GemmArgs gq{query, Wq, Qb, qscale};
  GemmArgs gk{key_t, Wk, Kb, qscale};
  GemmArgs gv{value, Wv, Vb, 1.0f};
  gemm_bt<true, false><<<dim3(8, 64, 3), 256, 0, stream>>>(gq, gk, gv);

  transpose_v<<<dim3(32, 64), 256, 0, stream>>>(Vb, Vt);

  attn_kernel<<<dim3(32, 64), 256, 0, stream>>>(Qb, Kb, Vt, mbits, pbits, alpha);

  GemmArgs go{alpha, Wo, d_out, 1.0f};
  gemm_bt<false, true><<<dim3(8, 64, 1), 256, 0, stream>>>(go, go, go);
}

// Round 2
// 369.290 us; speedup vs baseline: 1.5938x; 1.5938x over previous
//
#include <hip/hip_runtime.h>
#include <stdint.h>

#define B_  4
#define S_  2048
#define E_  1024
#define H_  16
#define D_  64
#define NEGV -1e20f

typedef __bf16 bf16;
typedef __bf16 bf16x4 __attribute__((ext_vector_type(4)));
typedef __bf16 bf16x8 __attribute__((ext_vector_type(8)));
typedef float  f32x4 __attribute__((ext_vector_type(4)));

__device__ __forceinline__ f32x4 mfma16(bf16x8 a, bf16x8 b, f32x4 c) {
  return __builtin_amdgcn_mfma_f32_16x16x32_bf16(a, b, c, 0, 0, 0);
}

// XOR swizzle in halfword units within a 64-halfword (128 B) row.
// Equivalent to chunk-granularity: chunk_lds = chunk_glb ^ (row & 7), 16B chunks.
__device__ __forceinline__ int sw(int row, int idx) { return idx ^ ((row & 7) << 3); }

// async global->LDS, 16B per lane. LDS dest must be wave-uniform base; HW adds lane*16.
__device__ __forceinline__ void gl_lds16(const void* g, void* l) {
  __builtin_amdgcn_global_load_lds(
      (const __attribute__((address_space(1))) void*)g,
      (__attribute__((address_space(3))) void*)l, 16, 0, 0);
}

// ---------------- mask packing ----------------
__global__ void pack_mask_kernel(const int* __restrict__ mask, uint32_t* __restrict__ mbits) {
  int idx = blockIdx.x * 256 + threadIdx.x;   // 2048*64 words
  int q = idx >> 6, w = idx & 63;
  const int* p = mask + q * S_ + w * 32;
  uint32_t bits = 0;
#pragma unroll
  for (int j = 0; j < 32; j += 4) {
    int4 v = *(const int4*)(p + j);
    bits |= (v.x != 0 ? 1u : 0u) << (j + 0);
    bits |= (v.y != 0 ? 1u : 0u) << (j + 1);
    bits |= (v.z != 0 ? 1u : 0u) << (j + 2);
    bits |= (v.w != 0 ? 1u : 0u) << (j + 3);
  }
  mbits[idx] = bits;
}

__global__ void pack_pad_kernel(const int* __restrict__ pad, uint32_t* __restrict__ pbits) {
  int idx = threadIdx.x;                      // 4*64 words
  int b = idx >> 6, w = idx & 63;
  const int* p = pad + b * S_ + w * 32;
  uint32_t bits = 0;
#pragma unroll
  for (int j = 0; j < 32; j += 4) {
    int4 v = *(const int4*)(p + j);
    bits |= (v.x != 0 ? 1u : 0u) << (j + 0);
    bits |= (v.y != 0 ? 1u : 0u) << (j + 1);
    bits |= (v.z != 0 ? 1u : 0u) << (j + 2);
    bits |= (v.w != 0 ? 1u : 0u) << (j + 3);
  }
  pbits[idx] = bits;
}

// ---------------- fp32 -> bf16 converts ----------------
__global__ __launch_bounds__(256)
void cvt_act(const float* __restrict__ q, const float* __restrict__ k,
             const float* __restrict__ v, bf16* __restrict__ out) {
  const float* src = blockIdx.z == 0 ? q : (blockIdx.z == 1 ? k : v);
  size_t i = ((size_t)blockIdx.x * 256 + threadIdx.x) * 8;
  float4 a = *(const float4*)(src + i);
  float4 b = *(const float4*)(src + i + 4);
  bf16x8 o;
  o[0] = (bf16)a.x; o[1] = (bf16)a.y; o[2] = (bf16)a.z; o[3] = (bf16)a.w;
  o[4] = (bf16)b.x; o[5] = (bf16)b.y; o[6] = (bf16)b.z; o[7] = (bf16)b.w;
  *(bf16x8*)(out + (size_t)blockIdx.z * (8192ull * 1024ull) + i) = o;
}

__global__ __launch_bounds__(256)
void cvt_w(const float* __restrict__ w0, const float* __restrict__ w1,
           const float* __restrict__ w2, const float* __restrict__ w3,
           bf16* __restrict__ out, float s01) {
  int z = blockIdx.z;
  const float* src = z == 0 ? w0 : (z == 1 ? w1 : (z == 2 ? w2 : w3));
  float s = (z < 2) ? s01 : 1.0f;
  size_t i = ((size_t)blockIdx.x * 256 + threadIdx.x) * 8;
  float4 a = *(const float4*)(src + i);
  float4 b = *(const float4*)(src + i + 4);
  bf16x8 o;
  o[0] = (bf16)(a.x * s); o[1] = (bf16)(a.y * s); o[2] = (bf16)(a.z * s); o[3] = (bf16)(a.w * s);
  o[4] = (bf16)(b.x * s); o[5] = (bf16)(b.y * s); o[6] = (bf16)(b.z * s); o[7] = (bf16)(b.w * s);
  *(bf16x8*)(out + (size_t)z * (1024ull * 1024ull) + i) = o;
}

// ---------------- GEMM: C = A @ W^T, bf16 operands, m97 structure ----------------
// A: [M][1024] bf16 row-major; W: [1024][1024] bf16 row-major. Both K-contiguous.
struct GA { const bf16* A; const bf16* W; void* O; };

template<bool OUT_F32>
__global__ __launch_bounds__(256, 2)
void gemm_bf(GA g0, GA g1, GA g2) {
  GA g = (blockIdx.z == 0) ? g0 : ((blockIdx.z == 1) ? g1 : g2);
  const int tid = threadIdx.x;
  const int l = tid & 63, wv = tid >> 6;
  const int lg = l >> 4, lr = l & 15;
  const int wr = wv >> 1, wc = wv & 1;
  const int brow = blockIdx.y * 128, bcol = blockIdx.x * 128;
  const int sr = l >> 3, sc8 = l & 7;          // staging: row-in-8-group, 16B chunk

  __shared__ bf16 As[128 * 64];
  __shared__ bf16 Bs[128 * 64];

  f32x4 acc[4][4] = {};

  // pre-swizzled global source: LDS is written linearly (base + lane*16B);
  // lane's global chunk = lds_chunk ^ (row&7). row&7 == sr here (8-row groups).
  const bf16* Ab = g.A + (size_t)(brow + wv * 32 + sr) * E_ + (size_t)(sc8 ^ sr) * 8;
  const bf16* Bb = g.W + (size_t)(bcol + wv * 32 + sr) * E_ + (size_t)(sc8 ^ sr) * 8;
  bf16* la = As + (wv * 32) * 64;
  bf16* lb = Bs + (wv * 32) * 64;

  for (int kt = 0; kt < E_ / 64; ++kt) {
    __syncthreads();
    const bf16* a = Ab + kt * 64;
    const bf16* b = Bb + kt * 64;
#pragma unroll
    for (int i = 0; i < 4; ++i) {
      gl_lds16(a + (size_t)i * 8 * E_, la + i * 8 * 64);
      gl_lds16(b + (size_t)i * 8 * E_, lb + i * 8 * 64);
    }
    __syncthreads();
#pragma unroll
    for (int kk = 0; kk < 2; ++kk) {
      bf16x8 af[4], bfr[4];
#pragma unroll
      for (int ms = 0; ms < 4; ++ms) {
        int row = wr * 64 + ms * 16 + lr;
        af[ms] = *(const bf16x8*)&As[sw(row, row * 64 + kk * 32 + lg * 8)];
      }
#pragma unroll
      for (int ns = 0; ns < 4; ++ns) {
        int row = wc * 64 + ns * 16 + lr;
        bfr[ns] = *(const bf16x8*)&Bs[sw(row, row * 64 + kk * 32 + lg * 8)];
      }
#pragma unroll
      for (int ms = 0; ms < 4; ++ms)
#pragma unroll
        for (int ns = 0; ns < 4; ++ns)
          acc[ms][ns] = mfma16(af[ms], bfr[ns], acc[ms][ns]);
    }
  }
  // ---- epilogue ----
#pragma unroll
  for (int ms = 0; ms < 4; ++ms) {
#pragma unroll
    for (int ns = 0; ns < 4; ++ns) {
#pragma unroll
      for (int r = 0; r < 4; ++r) {
        int row = brow + wr * 64 + ms * 16 + lg * 4 + r;
        int col = bcol + wc * 64 + ns * 16 + lr;
        if constexpr (OUT_F32) ((float*)g.O)[(size_t)row * E_ + col] = acc[ms][ns][r];
        else                   ((bf16*)g.O)[(size_t)row * E_ + col] = (bf16)acc[ms][ns][r];
      }
    }
  }
}

// ---------------- V transpose: V[b,s,h,d] -> Vt[b,h,d,s] ----------------
__global__ __launch_bounds__(256, 2)
void transpose_v(const bf16* __restrict__ V, bf16* __restrict__ Vt) {
  int bh = blockIdx.y; int b = bh >> 4, h = bh & 15;
  int s0 = blockIdx.x * 64;
  int tid = threadIdx.x;
  __shared__ bf16 t[64][72];
  int rb = tid >> 3, seg = tid & 7;
#pragma unroll
  for (int i = 0; i < 2; ++i) {
    int row = rb + 32 * i;
    bf16x8 v = *(const bf16x8*)(V + (size_t)(b * S_ + s0 + row) * E_ + h * 64 + seg * 8);
#pragma unroll
    for (int j = 0; j < 8; ++j) t[row][seg * 8 + j] = v[j];
  }
  __syncthreads();
#pragma unroll
  for (int i = 0; i < 2; ++i) {
    int d = rb + 32 * i;
    bf16x8 v;
#pragma unroll
    for (int j = 0; j < 8; ++j) v[j] = t[seg * 8 + j][d];
    *(bf16x8*)(Vt + ((size_t)bh * 64 + d) * S_ + s0 + seg * 8) = v;
  }
}

// ---------------- flash attention ----------------
__global__ __launch_bounds__(256, 2)
void attn_kernel(const bf16* __restrict__ Q, const bf16* __restrict__ K,
                 const bf16* __restrict__ Vt, const uint32_t* __restrict__ mbits,
                 const uint32_t* __restrict__ pbits, bf16* __restrict__ alpha) {
  const int bh = blockIdx.y, b = bh >> 4, h = bh & 15;
  const int tid = threadIdx.x, wv = tid >> 6, l = tid & 63;
  const int lg = l >> 4, lr = l & 15;
  const int q0 = blockIdx.x * 64 + wv * 16;
  const int sr = l >> 3, sc8 = l & 7;

  __shared__ bf16 Ks[64 * 64];      // [k-row][d], swizzled
  __shared__ bf16 Vs[64 * 64];      // [d][k], swizzled
  __shared__ bf16 Ps[4][16 * 64];   // per-wave P tile [q][k], swizzled

  bf16x8 qa[2];
#pragma unroll
  for (int kk = 0; kk < 2; ++kk)
    qa[kk] = *(const bf16x8*)(Q + (size_t)(b * S_ + q0 + lr) * E_ + h * 64 + kk * 32 + lg * 8);

  f32x4 o[4] = {};
  float m_run[4], l_run[4];
#pragma unroll
  for (int r = 0; r < 4; ++r) { m_run[r] = -__builtin_inff(); l_run[r] = 0.f; }

  // per-wave staging bases (pre-swizzled source chunks)
  const bf16* Kb0 = K + (size_t)(b * S_ + wv * 16 + sr) * E_ + h * 64 + (size_t)(sc8 ^ sr) * 8;
  const bf16* Vb0 = Vt + ((size_t)bh * 64 + wv * 16 + sr) * S_ + (size_t)(sc8 ^ sr) * 8;
  bf16* lk = Ks + (wv * 16) * 64;
  bf16* lv = Vs + (wv * 16) * 64;

  for (int kt = 0; kt < S_ / 64; ++kt) {
    __syncthreads();
    const bf16* kg = Kb0 + (size_t)kt * 64 * E_;
    const bf16* vg = Vb0 + (size_t)kt * 64;
    gl_lds16(kg, lk);
    gl_lds16(kg + (size_t)8 * E_, lk + 8 * 64);
    gl_lds16(vg, lv);
    gl_lds16(vg + (size_t)8 * S_, lv + 8 * 64);
    __syncthreads();

    // ---- scores: 16q x 64k ----
    f32x4 sc[4];
#pragma unroll
    for (int sub = 0; sub < 4; ++sub) {
      f32x4 s = {};
#pragma unroll
      for (int kk = 0; kk < 2; ++kk) {
        int row = sub * 16 + lr;
        bf16x8 kb = *(const bf16x8*)&Ks[sw(row, row * 64 + kk * 32 + lg * 8)];
        s = mfma16(qa[kk], kb, s);
      }
      sc[sub] = s;
    }

    // ---- masks ----
    uint32_t mw[4][2];
#pragma unroll
    for (int r = 0; r < 4; ++r) {
      int qg = q0 + lg * 4 + r;
      mw[r][0] = mbits[qg * 64 + kt * 2 + 0] & pbits[b * 64 + kt * 2 + 0];
      mw[r][1] = mbits[qg * 64 + kt * 2 + 1] & pbits[b * 64 + kt * 2 + 1];
    }

    // ---- online softmax ----
    float p[4][4];
#pragma unroll
    for (int r = 0; r < 4; ++r) {
      float vmax = -__builtin_inff();
#pragma unroll
      for (int sub = 0; sub < 4; ++sub) {
        uint32_t bit = (mw[r][sub >> 1] >> (((sub & 1) << 4) + lr)) & 1u;
        float s = bit ? sc[sub][r] : NEGV;
        sc[sub][r] = s;
        vmax = fmaxf(vmax, s);
      }
#pragma unroll
      for (int off = 1; off < 16; off <<= 1) vmax = fmaxf(vmax, __shfl_xor(vmax, off));
      float mnew = fmaxf(m_run[r], vmax);
      float scale = __expf(m_run[r] - mnew);
      m_run[r] = mnew;
      float psum = 0.f;
#pragma unroll
      for (int sub = 0; sub < 4; ++sub) {
        float pv = (sc[sub][r] <= 0.5f * NEGV) ? 0.f : __expf(sc[sub][r] - mnew);
        p[sub][r] = pv;
        psum += pv;
      }
#pragma unroll
      for (int off = 1; off < 16; off <<= 1) psum += __shfl_xor(psum, off);
      l_run[r] = l_run[r] * scale + psum;
#pragma unroll
      for (int ds = 0; ds < 4; ++ds) o[ds][r] *= scale;
    }

    // ---- P -> LDS (per-wave) ----
#pragma unroll
    for (int sub = 0; sub < 4; ++sub)
#pragma unroll
      for (int r = 0; r < 4; ++r) {
        int row = lg * 4 + r;
        Ps[wv][sw(row, row * 64 + sub * 16 + lr)] = (bf16)p[sub][r];
      }

    // ---- PV ----
#pragma unroll
    for (int kc = 0; kc < 2; ++kc) {
      bf16x8 pa = *(const bf16x8*)&Ps[wv][sw(lr, lr * 64 + kc * 32 + lg * 8)];
#pragma unroll
      for (int ds = 0; ds < 4; ++ds) {
        int row = ds * 16 + lr;
        bf16x8 vb = *(const bf16x8*)&Vs[sw(row, row * 64 + kc * 32 + lg * 8)];
        o[ds] = mfma16(pa, vb, o[ds]);
      }
    }
  }

  // ---- epilogue: alpha = o / l ----
#pragma unroll
  for (int r = 0; r < 4; ++r) {
    float inv = 1.0f / l_run[r];
#pragma unroll
    for (int ds = 0; ds < 4; ++ds) {
      int row = q0 + lg * 4 + r;
      int col = h * 64 + ds * 16 + lr;
      alpha[(size_t)(b * S_ + row) * E_ + col] = (bf16)(o[ds][r] * inv);
    }
  }
}

// ---------------- launch ----------------
extern "C" void kernel_launch(void* const* d_in, const int* in_sizes, int n_in,
                              void* d_out, int out_size, void* d_ws, size_t ws_size,
                              hipStream_t stream) {
  const float* query = (const float*)d_in[0];
  const float* key_t = (const float*)d_in[1];
  const float* value = (const float*)d_in[2];
  const int*   mask  = (const int*)d_in[3];
  const int*   pad   = (const int*)d_in[4];
  const float* Wq    = (const float*)d_in[5];
  const float* Wk    = (const float*)d_in[6];
  const float* Wv    = (const float*)d_in[7];
  const float* Wo    = (const float*)d_in[8];

  char* ws = (char*)d_ws;
  // [0, 48M):   Abuf (bf16 activations, 3 x 8192 x 1024) -- consumed by QKV gemm,
  //             then reused: Vt at [0,16M), alpha at [16M,32M)
  // [48M, 56M): Wb (bf16 weights, 4 x 1024 x 1024; Wq/Wk pre-scaled)
  // [56M, 104M): QKV bf16 outputs (Qb, Kb, Vb)
  // [104M, ...): mbits (512K) + pbits
  bf16* Abuf = (bf16*)ws;
  bf16* Vt    = (bf16*)ws;
  bf16* alpha = (bf16*)(ws + ((size_t)16 << 20));
  bf16* Wb   = (bf16*)(ws + ((size_t)48 << 20));
  bf16* QKV  = (bf16*)(ws + ((size_t)56 << 20));
  uint32_t* mbits = (uint32_t*)(ws + ((size_t)104 << 20));
  uint32_t* pbits = mbits + (size_t)S_ * 64;

  const size_t AM = 8192ull * 1024ull;   // activation matrix elems
  const size_t WM = 1024ull * 1024ull;   // weight matrix elems

  pack_mask_kernel<<<512, 256, 0, stream>>>(mask, mbits);
  pack_pad_kernel<<<1, 256, 0, stream>>>(pad, pbits);

  cvt_act<<<dim3(4096, 1, 3), 256, 0, stream>>>(query, key_t, value, Abuf);
  const float qscale = 0.17677669529663687f;  // 1024^-0.25
  cvt_w<<<dim3(512, 1, 4), 256, 0, stream>>>(Wq, Wk, Wv, Wo, Wb, qscale);

  GA gq{Abuf,          Wb,          QKV};
  GA gk{Abuf + AM,     Wb + WM,     QKV + AM};
  GA gv{Abuf + 2 * AM, Wb + 2 * WM, QKV + 2 * AM};
  gemm_bf<false><<<dim3(8, 64, 3), 256, 0, stream>>>(gq, gk, gv);

  transpose_v<<<dim3(32, 64), 256, 0, stream>>>(QKV + 2 * AM, Vt);

  attn_kernel<<<dim3(32, 64), 256, 0, stream>>>(QKV, QKV + AM, Vt, mbits, pbits, alpha);

  GA go{alpha, Wb + 3 * WM, d_out};
  gemm_bf<true><<<dim3(8, 64, 1), 256, 0, stream>>>(go, go, go);
}

// Round 3
// 285.449 us; speedup vs baseline: 2.0619x; 1.2937x over previous
//
#include <hip/hip_runtime.h>
#include <stdint.h>

#define B_  4
#define S_  2048
#define E_  1024
#define H_  16
#define D_  64
#define NEGV -1e20f

typedef __bf16 bf16;
typedef __bf16 bf16x2 __attribute__((ext_vector_type(2)));
typedef __bf16 bf16x4 __attribute__((ext_vector_type(4)));
typedef __bf16 bf16x8 __attribute__((ext_vector_type(8)));
typedef float  f32x4 __attribute__((ext_vector_type(4)));

__device__ __forceinline__ f32x4 mfma16(bf16x8 a, bf16x8 b, f32x4 c) {
  return __builtin_amdgcn_mfma_f32_16x16x32_bf16(a, b, c, 0, 0, 0);
}

// XOR swizzle in halfword units within a 64-halfword (128 B) row.
__device__ __forceinline__ int sw(int row, int idx) { return idx ^ ((row & 7) << 3); }

// async global->LDS, 16B per lane. LDS dest is wave-uniform base; HW adds lane*16.
__device__ __forceinline__ void gl_lds16(const void* g, void* l) {
  __builtin_amdgcn_global_load_lds(
      (const __attribute__((address_space(1))) void*)g,
      (__attribute__((address_space(3))) void*)l, 16, 0, 0);
}

// ---------------- mask packing ----------------
__global__ void pack_mask_kernel(const int* __restrict__ mask, uint32_t* __restrict__ mbits) {
  int idx = blockIdx.x * 256 + threadIdx.x;   // 2048*64 words
  int q = idx >> 6, w = idx & 63;
  const int* p = mask + q * S_ + w * 32;
  uint32_t bits = 0;
#pragma unroll
  for (int j = 0; j < 32; j += 4) {
    int4 v = *(const int4*)(p + j);
    bits |= (v.x != 0 ? 1u : 0u) << (j + 0);
    bits |= (v.y != 0 ? 1u : 0u) << (j + 1);
    bits |= (v.z != 0 ? 1u : 0u) << (j + 2);
    bits |= (v.w != 0 ? 1u : 0u) << (j + 3);
  }
  mbits[idx] = bits;
}

__global__ void pack_pad_kernel(const int* __restrict__ pad, uint32_t* __restrict__ pbits) {
  int idx = threadIdx.x;                      // 4*64 words
  int b = idx >> 6, w = idx & 63;
  const int* p = pad + b * S_ + w * 32;
  uint32_t bits = 0;
#pragma unroll
  for (int j = 0; j < 32; j += 4) {
    int4 v = *(const int4*)(p + j);
    bits |= (v.x != 0 ? 1u : 0u) << (j + 0);
    bits |= (v.y != 0 ? 1u : 0u) << (j + 1);
    bits |= (v.z != 0 ? 1u : 0u) << (j + 2);
    bits |= (v.w != 0 ? 1u : 0u) << (j + 3);
  }
  pbits[idx] = bits;
}

// ---------------- fp32 -> bf16 converts ----------------
__global__ __launch_bounds__(256)
void cvt_act(const float* __restrict__ q, const float* __restrict__ k,
             const float* __restrict__ v, bf16* __restrict__ out) {
  const float* src = blockIdx.z == 0 ? q : (blockIdx.z == 1 ? k : v);
  size_t i = ((size_t)blockIdx.x * 256 + threadIdx.x) * 8;
  float4 a = *(const float4*)(src + i);
  float4 b = *(const float4*)(src + i + 4);
  bf16x8 o;
  o[0] = (bf16)a.x; o[1] = (bf16)a.y; o[2] = (bf16)a.z; o[3] = (bf16)a.w;
  o[4] = (bf16)b.x; o[5] = (bf16)b.y; o[6] = (bf16)b.z; o[7] = (bf16)b.w;
  *(bf16x8*)(out + (size_t)blockIdx.z * (8192ull * 1024ull) + i) = o;
}

__global__ __launch_bounds__(256)
void cvt_w(const float* __restrict__ w0, const float* __restrict__ w1,
           const float* __restrict__ w2, const float* __restrict__ w3,
           bf16* __restrict__ out, float sq, float sk) {
  int z = blockIdx.z;
  const float* src = z == 0 ? w0 : (z == 1 ? w1 : (z == 2 ? w2 : w3));
  float s = (z == 0) ? sq : ((z == 1) ? sk : 1.0f);
  size_t i = ((size_t)blockIdx.x * 256 + threadIdx.x) * 8;
  float4 a = *(const float4*)(src + i);
  float4 b = *(const float4*)(src + i + 4);
  bf16x8 o;
  o[0] = (bf16)(a.x * s); o[1] = (bf16)(a.y * s); o[2] = (bf16)(a.z * s); o[3] = (bf16)(a.w * s);
  o[4] = (bf16)(b.x * s); o[5] = (bf16)(b.y * s); o[6] = (bf16)(b.z * s); o[7] = (bf16)(b.w * s);
  *(bf16x8*)(out + (size_t)z * (1024ull * 1024ull) + i) = o;
}

// ---------------- GEMM: C = A @ W^T, bf16 operands ----------------
// grid.x = row panel (L2 locality: same panel -> same XCD), grid.y = col panel
struct GA { const bf16* A; const bf16* W; void* O; };

template<bool OUT_F32>
__global__ __launch_bounds__(256, 2)
void gemm_bf(GA g0, GA g1, GA g2) {
  GA g = (blockIdx.z == 0) ? g0 : ((blockIdx.z == 1) ? g1 : g2);
  const int tid = threadIdx.x;
  const int l = tid & 63, wv = tid >> 6;
  const int lg = l >> 4, lr = l & 15;
  const int wr = wv >> 1, wc = wv & 1;
  const int brow = blockIdx.x * 128, bcol = blockIdx.y * 128;
  const int sr = l >> 3, sc8 = l & 7;

  __shared__ bf16 As[128 * 64];
  __shared__ bf16 Bs[128 * 64];

  f32x4 acc[4][4] = {};

  const bf16* Ab = g.A + (size_t)(brow + wv * 32 + sr) * E_ + (size_t)(sc8 ^ sr) * 8;
  const bf16* Bb = g.W + (size_t)(bcol + wv * 32 + sr) * E_ + (size_t)(sc8 ^ sr) * 8;
  bf16* la = As + (wv * 32) * 64;
  bf16* lb = Bs + (wv * 32) * 64;

  for (int kt = 0; kt < E_ / 64; ++kt) {
    __syncthreads();
    const bf16* a = Ab + kt * 64;
    const bf16* b = Bb + kt * 64;
#pragma unroll
    for (int i = 0; i < 4; ++i) {
      gl_lds16(a + (size_t)i * 8 * E_, la + i * 8 * 64);
      gl_lds16(b + (size_t)i * 8 * E_, lb + i * 8 * 64);
    }
    __syncthreads();
#pragma unroll
    for (int kk = 0; kk < 2; ++kk) {
      bf16x8 af[4], bfr[4];
#pragma unroll
      for (int ms = 0; ms < 4; ++ms) {
        int row = wr * 64 + ms * 16 + lr;
        af[ms] = *(const bf16x8*)&As[sw(row, row * 64 + kk * 32 + lg * 8)];
      }
#pragma unroll
      for (int ns = 0; ns < 4; ++ns) {
        int row = wc * 64 + ns * 16 + lr;
        bfr[ns] = *(const bf16x8*)&Bs[sw(row, row * 64 + kk * 32 + lg * 8)];
      }
#pragma unroll
      for (int ms = 0; ms < 4; ++ms)
#pragma unroll
        for (int ns = 0; ns < 4; ++ns)
          acc[ms][ns] = mfma16(af[ms], bfr[ns], acc[ms][ns]);
    }
  }
#pragma unroll
  for (int ms = 0; ms < 4; ++ms) {
#pragma unroll
    for (int ns = 0; ns < 4; ++ns) {
#pragma unroll
      for (int r = 0; r < 4; ++r) {
        int row = brow + wr * 64 + ms * 16 + lg * 4 + r;
        int col = bcol + wc * 64 + ns * 16 + lr;
        if constexpr (OUT_F32) ((float*)g.O)[(size_t)row * E_ + col] = acc[ms][ns][r];
        else                   ((bf16*)g.O)[(size_t)row * E_ + col] = (bf16)acc[ms][ns][r];
      }
    }
  }
}

// ---------------- V transpose: V[b,s,h,d] -> Vt[b,h,d,s] ----------------
__global__ __launch_bounds__(256, 2)
void transpose_v(const bf16* __restrict__ V, bf16* __restrict__ Vt) {
  int bh = blockIdx.y; int b = bh >> 4, h = bh & 15;
  int s0 = blockIdx.x * 64;
  int tid = threadIdx.x;
  __shared__ bf16 t[64][72];
  int rb = tid >> 3, seg = tid & 7;
#pragma unroll
  for (int i = 0; i < 2; ++i) {
    int row = rb + 32 * i;
    bf16x8 v = *(const bf16x8*)(V + (size_t)(b * S_ + s0 + row) * E_ + h * 64 + seg * 8);
#pragma unroll
    for (int j = 0; j < 8; ++j) t[row][seg * 8 + j] = v[j];
  }
  __syncthreads();
#pragma unroll
  for (int i = 0; i < 2; ++i) {
    int d = rb + 32 * i;
    bf16x8 v;
#pragma unroll
    for (int j = 0; j < 8; ++j) v[j] = t[seg * 8 + j][d];
    *(bf16x8*)(Vt + ((size_t)bh * 64 + d) * S_ + s0 + seg * 8) = v;
  }
}

// ---------------- flash attention (swapped operands, log2 domain) ----------------
// grid: x = bh (64), y = q-block (32). Scores S^T[k][q]; O^T[d][q] per wave.
__global__ __launch_bounds__(256, 4)
void attn_kernel(const bf16* __restrict__ Q, const bf16* __restrict__ K,
                 const bf16* __restrict__ Vt, const uint32_t* __restrict__ mbits,
                 const uint32_t* __restrict__ pbits, bf16* __restrict__ alpha) {
  const int bh = blockIdx.x, b = bh >> 4, h = bh & 15;
  const int tid = threadIdx.x, wv = tid >> 6, l = tid & 63;
  const int lg = l >> 4, lr = l & 15;
  const int q0 = blockIdx.y * 64 + wv * 16;
  const int sr = l >> 3, sc8 = l & 7;

  __shared__ bf16 Ks[2][64 * 64];   // [k-row][d], swizzled
  __shared__ bf16 Vs[2][64 * 64];   // [d][k], swizzled
  __shared__ bf16 Ps[4][16 * 64];   // per-wave P [q][k], swizzled

  // Q as B-operand: lane holds Q[q0+lr][kk*32+lg*8 .. +8]  (Wq pre-scaled by log2e)
  bf16x8 qa[2];
#pragma unroll
  for (int kk = 0; kk < 2; ++kk)
    qa[kk] = *(const bf16x8*)(Q + (size_t)(b * S_ + q0 + lr) * E_ + h * 64 + kk * 32 + lg * 8);

  f32x4 o[4] = {};              // o[ds][r]: d = ds*16+lg*4+r, q = lr
  float m_run = -4e19f, l_run = 0.f;

  const bf16* Kb0 = K + (size_t)(b * S_ + wv * 16 + sr) * E_ + h * 64 + (size_t)(sc8 ^ sr) * 8;
  const bf16* Vb0 = Vt + ((size_t)bh * 64 + wv * 16 + sr) * S_ + (size_t)(sc8 ^ sr) * 8;

  auto stage = [&](int buf, int kt) {
    const bf16* kg = Kb0 + (size_t)kt * 64 * E_;
    const bf16* vg = Vb0 + (size_t)kt * 64;
    bf16* lk = Ks[buf] + (wv * 16) * 64;
    bf16* lv = Vs[buf] + (wv * 16) * 64;
    gl_lds16(kg, lk);
    gl_lds16(kg + (size_t)8 * E_, lk + 8 * 64);
    gl_lds16(vg, lv);
    gl_lds16(vg + (size_t)8 * S_, lv + 8 * 64);
  };

  stage(0, 0);
  __syncthreads();   // compiler drains vmcnt before barrier -> tile 0 ready

  for (int kt = 0; kt < S_ / 64; ++kt) {
    const int cur = kt & 1;
    if (kt + 1 < S_ / 64) stage(cur ^ 1, kt + 1);   // lands at end-of-iter barrier

    // masks for this tile (q = q0+lr): one u64 + scalar pad words
    uint32_t pw0 = pbits[b * 64 + kt * 2], pw1 = pbits[b * 64 + kt * 2 + 1];
    uint2 mv = *(const uint2*)(mbits + (size_t)(q0 + lr) * 64 + kt * 2);
    uint32_t w0s = (mv.x & pw0) >> (lg * 4);
    uint32_t w1s = (mv.y & pw1) >> (lg * 4);

    // ---- QK^T swapped: sc[sub][r] = S^T[k = sub*16+lg*4+r][q = lr] ----
    f32x4 sc[4];
#pragma unroll
    for (int sub = 0; sub < 4; ++sub) {
      f32x4 s = {};
#pragma unroll
      for (int kk = 0; kk < 2; ++kk) {
        int row = sub * 16 + lr;
        bf16x8 kb = *(const bf16x8*)&Ks[cur][sw(row, row * 64 + kk * 32 + lg * 8)];
        s = mfma16(kb, qa[kk], s);
      }
      sc[sub] = s;
    }

    // ---- in-lane max (unmasked: shift cancels in o/l) + cross-lg reduce ----
    float sm[4];
#pragma unroll
    for (int sub = 0; sub < 4; ++sub)
      sm[sub] = fmaxf(fmaxf(sc[sub][0], sc[sub][1]), fmaxf(sc[sub][2], sc[sub][3]));
    float tmax = fmaxf(fmaxf(sm[0], sm[1]), fmaxf(sm[2], sm[3]));
    tmax = fmaxf(tmax, __shfl_xor(tmax, 16));
    tmax = fmaxf(tmax, __shfl_xor(tmax, 32));

    // ---- defer-max rescale ----
    if (!__all(tmax <= m_run + 10.f)) {
      float mnew = fmaxf(m_run, tmax);
      float rs = __builtin_amdgcn_exp2f(m_run - mnew);
      m_run = mnew;
      l_run *= rs;
#pragma unroll
      for (int ds = 0; ds < 4; ++ds) o[ds] = o[ds] * rs;
    }

    // ---- p = exp2(s - m) masked; sum ----
    float p[4][4], ss[4];
#pragma unroll
    for (int sub = 0; sub < 4; ++sub) {
      uint32_t ws = (sub & 2) ? w1s : w0s;
#pragma unroll
      for (int r = 0; r < 4; ++r) {
        float pe = __builtin_amdgcn_exp2f(sc[sub][r] - m_run);
        uint32_t bit = (ws >> (((sub & 1) << 4) + r)) & 1u;
        p[sub][r] = bit ? pe : 0.f;
      }
      ss[sub] = (p[sub][0] + p[sub][1]) + (p[sub][2] + p[sub][3]);
    }
    float psum = (ss[0] + ss[1]) + (ss[2] + ss[3]);
    psum += __shfl_xor(psum, 16);
    psum += __shfl_xor(psum, 32);
    l_run += psum;

    // ---- P -> per-wave LDS as bf16 pairs (8x ds_write_b32) ----
#pragma unroll
    for (int sub = 0; sub < 4; ++sub)
#pragma unroll
      for (int t = 0; t < 2; ++t) {
        bf16x2 pr; pr[0] = (bf16)p[sub][2 * t]; pr[1] = (bf16)p[sub][2 * t + 1];
        *(bf16x2*)&Ps[wv][sw(lr, lr * 64 + sub * 16 + lg * 4 + 2 * t)] = pr;
      }

    // ---- PV swapped: o[ds] += Vt_sub . P^T ----
#pragma unroll
    for (int kc = 0; kc < 2; ++kc) {
      bf16x8 pa = *(const bf16x8*)&Ps[wv][sw(lr, lr * 64 + kc * 32 + lg * 8)];
#pragma unroll
      for (int ds = 0; ds < 4; ++ds) {
        int row = ds * 16 + lr;
        bf16x8 vb = *(const bf16x8*)&Vs[cur][sw(row, row * 64 + kc * 32 + lg * 8)];
        o[ds] = mfma16(vb, pa, o[ds]);
      }
    }
    __syncthreads();   // drains next-tile stage + protects buffer reuse
  }

  // ---- epilogue: alpha[b, q, h*64 + d] = o/l ----
  float inv = 1.0f / l_run;
#pragma unroll
  for (int ds = 0; ds < 4; ++ds) {
    bf16x4 ov;
#pragma unroll
    for (int r = 0; r < 4; ++r) ov[r] = (bf16)(o[ds][r] * inv);
    *(bf16x4*)(alpha + (size_t)(b * S_ + q0 + lr) * E_ + h * 64 + ds * 16 + lg * 4) = ov;
  }
}

// ---------------- launch ----------------
extern "C" void kernel_launch(void* const* d_in, const int* in_sizes, int n_in,
                              void* d_out, int out_size, void* d_ws, size_t ws_size,
                              hipStream_t stream) {
  const float* query = (const float*)d_in[0];
  const float* key_t = (const float*)d_in[1];
  const float* value = (const float*)d_in[2];
  const int*   mask  = (const int*)d_in[3];
  const int*   pad   = (const int*)d_in[4];
  const float* Wq    = (const float*)d_in[5];
  const float* Wk    = (const float*)d_in[6];
  const float* Wv    = (const float*)d_in[7];
  const float* Wo    = (const float*)d_in[8];

  char* ws = (char*)d_ws;
  bf16* Abuf = (bf16*)ws;                              // 48M, then reused below
  bf16* Vt    = (bf16*)ws;                             // 16M
  bf16* alpha = (bf16*)(ws + ((size_t)16 << 20));      // 16M
  bf16* Wb   = (bf16*)(ws + ((size_t)48 << 20));       // 8M
  bf16* QKV  = (bf16*)(ws + ((size_t)56 << 20));       // 48M
  uint32_t* mbits = (uint32_t*)(ws + ((size_t)104 << 20));
  uint32_t* pbits = mbits + (size_t)S_ * 64;

  const size_t AM = 8192ull * 1024ull;
  const size_t WM = 1024ull * 1024ull;

  pack_mask_kernel<<<512, 256, 0, stream>>>(mask, mbits);
  pack_pad_kernel<<<1, 256, 0, stream>>>(pad, pbits);

  cvt_act<<<dim3(4096, 1, 3), 256, 0, stream>>>(query, key_t, value, Abuf);
  const float qscale = 0.17677669529663687f;           // 1024^-0.25
  const float log2e  = 1.4426950408889634f;
  cvt_w<<<dim3(512, 1, 4), 256, 0, stream>>>(Wq, Wk, Wv, Wo, Wb, qscale * log2e, qscale);

  GA gq{Abuf,          Wb,          QKV};
  GA gk{Abuf + AM,     Wb + WM,     QKV + AM};
  GA gv{Abuf + 2 * AM, Wb + 2 * WM, QKV + 2 * AM};
  gemm_bf<false><<<dim3(64, 8, 3), 256, 0, stream>>>(gq, gk, gv);

  transpose_v<<<dim3(32, 64), 256, 0, stream>>>(QKV + 2 * AM, Vt);

  attn_kernel<<<dim3(64, 32), 256, 0, stream>>>(QKV, QKV + AM, Vt, mbits, pbits, alpha);

  GA go{alpha, Wb + 3 * WM, d_out};
  gemm_bf<true><<<dim3(64, 8, 1), 256, 0, stream>>>(go, go, go);
}

// Round 4
// 258.126 us; speedup vs baseline: 2.2801x; 1.1058x over previous
//
#include <hip/hip_runtime.h>
#include <stdint.h>

#define B_  4
#define S_  2048
#define E_  1024
#define H_  16
#define D_  64

typedef __bf16 bf16;
typedef __bf16 bf16x4 __attribute__((ext_vector_type(4)));
typedef __bf16 bf16x8 __attribute__((ext_vector_type(8)));
typedef float  f32x4 __attribute__((ext_vector_type(4)));
typedef float  f32x16 __attribute__((ext_vector_type(16)));
typedef uint32_t u32x4 __attribute__((ext_vector_type(4)));

__device__ __forceinline__ f32x4 mfma16(bf16x8 a, bf16x8 b, f32x4 c) {
  return __builtin_amdgcn_mfma_f32_16x16x32_bf16(a, b, c, 0, 0, 0);
}
__device__ __forceinline__ f32x16 mfma32(bf16x8 a, bf16x8 b, f32x16 c) {
  return __builtin_amdgcn_mfma_f32_32x32x16_bf16(a, b, c, 0, 0, 0);
}

// GEMM swizzle (16-row frag groups): chunk ^= row&7
__device__ __forceinline__ int sw(int row, int idx) { return idx ^ ((row & 7) << 3); }

__device__ __forceinline__ void gl_lds16(const void* g, void* l) {
  __builtin_amdgcn_global_load_lds(
      (const __attribute__((address_space(1))) void*)g,
      (__attribute__((address_space(3))) void*)l, 16, 0, 0);
}

__device__ __forceinline__ uint32_t cvtpk(float lo, float hi) {
  uint32_t r;
  asm("v_cvt_pk_bf16_f32 %0, %1, %2" : "=v"(r) : "v"(lo), "v"(hi));
  return r;
}
__device__ __forceinline__ void plswap(uint32_t& a, uint32_t& b) {
  asm("v_permlane32_swap_b32 %0, %1" : "+v"(a), "+v"(b));
}

// ---------------- mask packing ----------------
__global__ void pack_mask_kernel(const int* __restrict__ mask, uint32_t* __restrict__ mbits) {
  int idx = blockIdx.x * 256 + threadIdx.x;
  int q = idx >> 6, w = idx & 63;
  const int* p = mask + q * S_ + w * 32;
  uint32_t bits = 0;
#pragma unroll
  for (int j = 0; j < 32; j += 4) {
    int4 v = *(const int4*)(p + j);
    bits |= (v.x != 0 ? 1u : 0u) << (j + 0);
    bits |= (v.y != 0 ? 1u : 0u) << (j + 1);
    bits |= (v.z != 0 ? 1u : 0u) << (j + 2);
    bits |= (v.w != 0 ? 1u : 0u) << (j + 3);
  }
  mbits[idx] = bits;
}

__global__ void pack_pad_kernel(const int* __restrict__ pad, uint32_t* __restrict__ pbits) {
  int idx = threadIdx.x;
  int b = idx >> 6, w = idx & 63;
  const int* p = pad + b * S_ + w * 32;
  uint32_t bits = 0;
#pragma unroll
  for (int j = 0; j < 32; j += 4) {
    int4 v = *(const int4*)(p + j);
    bits |= (v.x != 0 ? 1u : 0u) << (j + 0);
    bits |= (v.y != 0 ? 1u : 0u) << (j + 1);
    bits |= (v.z != 0 ? 1u : 0u) << (j + 2);
    bits |= (v.w != 0 ? 1u : 0u) << (j + 3);
  }
  pbits[idx] = bits;
}

// ---------------- fp32 -> bf16 converts ----------------
__global__ __launch_bounds__(256)
void cvt_act(const float* __restrict__ q, const float* __restrict__ k,
             const float* __restrict__ v, bf16* __restrict__ out) {
  const float* src = blockIdx.z == 0 ? q : (blockIdx.z == 1 ? k : v);
  size_t i = ((size_t)blockIdx.x * 256 + threadIdx.x) * 8;
  float4 a = *(const float4*)(src + i);
  float4 b = *(const float4*)(src + i + 4);
  bf16x8 o;
  o[0] = (bf16)a.x; o[1] = (bf16)a.y; o[2] = (bf16)a.z; o[3] = (bf16)a.w;
  o[4] = (bf16)b.x; o[5] = (bf16)b.y; o[6] = (bf16)b.z; o[7] = (bf16)b.w;
  *(bf16x8*)(out + (size_t)blockIdx.z * (8192ull * 1024ull) + i) = o;
}

__global__ __launch_bounds__(256)
void cvt_w(const float* __restrict__ w0, const float* __restrict__ w1,
           const float* __restrict__ w2, const float* __restrict__ w3,
           bf16* __restrict__ out, float sq, float sk) {
  int z = blockIdx.z;
  const float* src = z == 0 ? w0 : (z == 1 ? w1 : (z == 2 ? w2 : w3));
  float s = (z == 0) ? sq : ((z == 1) ? sk : 1.0f);
  size_t i = ((size_t)blockIdx.x * 256 + threadIdx.x) * 8;
  float4 a = *(const float4*)(src + i);
  float4 b = *(const float4*)(src + i + 4);
  bf16x8 o;
  o[0] = (bf16)(a.x * s); o[1] = (bf16)(a.y * s); o[2] = (bf16)(a.z * s); o[3] = (bf16)(a.w * s);
  o[4] = (bf16)(b.x * s); o[5] = (bf16)(b.y * s); o[6] = (bf16)(b.z * s); o[7] = (bf16)(b.w * s);
  *(bf16x8*)(out + (size_t)z * (1024ull * 1024ull) + i) = o;
}

// ---------------- GEMM: C = A @ W^T (unchanged m97-style) ----------------
struct GA { const bf16* A; const bf16* W; void* O; };

template<bool OUT_F32>
__global__ __launch_bounds__(256, 2)
void gemm_bf(GA g0, GA g1, GA g2) {
  GA g = (blockIdx.z == 0) ? g0 : ((blockIdx.z == 1) ? g1 : g2);
  const int tid = threadIdx.x;
  const int l = tid & 63, wv = tid >> 6;
  const int lg = l >> 4, lr = l & 15;
  const int wr = wv >> 1, wc = wv & 1;
  const int brow = blockIdx.x * 128, bcol = blockIdx.y * 128;
  const int sr = l >> 3, sc8 = l & 7;

  __shared__ bf16 As[128 * 64];
  __shared__ bf16 Bs[128 * 64];

  f32x4 acc[4][4] = {};

  const bf16* Ab = g.A + (size_t)(brow + wv * 32 + sr) * E_ + (size_t)(sc8 ^ sr) * 8;
  const bf16* Bb = g.W + (size_t)(bcol + wv * 32 + sr) * E_ + (size_t)(sc8 ^ sr) * 8;
  bf16* la = As + (wv * 32) * 64;
  bf16* lb = Bs + (wv * 32) * 64;

  for (int kt = 0; kt < E_ / 64; ++kt) {
    __syncthreads();
    const bf16* a = Ab + kt * 64;
    const bf16* b = Bb + kt * 64;
#pragma unroll
    for (int i = 0; i < 4; ++i) {
      gl_lds16(a + (size_t)i * 8 * E_, la + i * 8 * 64);
      gl_lds16(b + (size_t)i * 8 * E_, lb + i * 8 * 64);
    }
    __syncthreads();
#pragma unroll
    for (int kk = 0; kk < 2; ++kk) {
      bf16x8 af[4], bfr[4];
#pragma unroll
      for (int ms = 0; ms < 4; ++ms) {
        int row = wr * 64 + ms * 16 + lr;
        af[ms] = *(const bf16x8*)&As[sw(row, row * 64 + kk * 32 + lg * 8)];
      }
#pragma unroll
      for (int ns = 0; ns < 4; ++ns) {
        int row = wc * 64 + ns * 16 + lr;
        bfr[ns] = *(const bf16x8*)&Bs[sw(row, row * 64 + kk * 32 + lg * 8)];
      }
#pragma unroll
      for (int ms = 0; ms < 4; ++ms)
#pragma unroll
        for (int ns = 0; ns < 4; ++ns)
          acc[ms][ns] = mfma16(af[ms], bfr[ns], acc[ms][ns]);
    }
  }
#pragma unroll
  for (int ms = 0; ms < 4; ++ms) {
#pragma unroll
    for (int ns = 0; ns < 4; ++ns) {
#pragma unroll
      for (int r = 0; r < 4; ++r) {
        int row = brow + wr * 64 + ms * 16 + lg * 4 + r;
        int col = bcol + wc * 64 + ns * 16 + lr;
        if constexpr (OUT_F32) ((float*)g.O)[(size_t)row * E_ + col] = acc[ms][ns][r];
        else                   ((bf16*)g.O)[(size_t)row * E_ + col] = (bf16)acc[ms][ns][r];
      }
    }
  }
}

// ---------------- V transpose ----------------
__global__ __launch_bounds__(256, 2)
void transpose_v(const bf16* __restrict__ V, bf16* __restrict__ Vt) {
  int bh = blockIdx.y; int b = bh >> 4, h = bh & 15;
  int s0 = blockIdx.x * 64;
  int tid = threadIdx.x;
  __shared__ bf16 t[64][72];
  int rb = tid >> 3, seg = tid & 7;
#pragma unroll
  for (int i = 0; i < 2; ++i) {
    int row = rb + 32 * i;
    bf16x8 v = *(const bf16x8*)(V + (size_t)(b * S_ + s0 + row) * E_ + h * 64 + seg * 8);
#pragma unroll
    for (int j = 0; j < 8; ++j) t[row][seg * 8 + j] = v[j];
  }
  __syncthreads();
#pragma unroll
  for (int i = 0; i < 2; ++i) {
    int d = rb + 32 * i;
    bf16x8 v;
#pragma unroll
    for (int j = 0; j < 8; ++j) v[j] = t[seg * 8 + j][d];
    *(bf16x8*)(Vt + ((size_t)bh * 64 + d) * S_ + s0 + seg * 8) = v;
  }
}

// ---------------- flash attention: 32x32 MFMA, 64q/wave, in-register P ----------------
// grid(512): raw -> xcd=raw&7 owns bh in [xcd*8, xcd*8+8)
__global__ __launch_bounds__(256, 2)
void attn_kernel(const bf16* __restrict__ Q, const bf16* __restrict__ K,
                 const bf16* __restrict__ Vt, const uint32_t* __restrict__ mbits,
                 const uint32_t* __restrict__ pbits, bf16* __restrict__ alpha) {
  const int raw = blockIdx.x;
  const int xcd = raw & 7, slot = raw >> 3;
  const int bh = xcd * 8 + (slot >> 3), qblk = slot & 7;
  const int b = bh >> 4, h = bh & 15;
  const int tid = threadIdx.x, wv = tid >> 6, l = tid & 63;
  const int ln = l & 31, hi = l >> 5;
  const int qw = qblk * 256 + wv * 64;
  const int sr = l >> 3, sc8 = l & 7;
  const int g = (ln & 7) ^ (ln >> 3);      // read-side row-hash

  __shared__ bf16 Ks[2][64 * 64];          // [k][d], swizzled chunks
  __shared__ bf16 Vs[2][64 * 64];          // [d][k], swizzled chunks

  // Q fragments in registers: qreg[qt][dc] = Q[qw+qt*32+ln][dc*16+hi*8 ..+8]
  bf16x8 qreg[2][4];
#pragma unroll
  for (int qt = 0; qt < 2; ++qt)
#pragma unroll
    for (int dc = 0; dc < 4; ++dc)
      qreg[qt][dc] = *(const bf16x8*)(Q + (size_t)(b * S_ + qw + qt * 32 + ln) * E_
                                        + h * 64 + dc * 16 + hi * 8);

  f32x16 o[2][2] = {};                     // o[dt][qt]
  float m_run[2] = {-4e19f, -4e19f}, l_run[2] = {0.f, 0.f};

  // staging bases; source chunk pre-swizzled: sc8 ^ sr ^ ((rb>>3)&7)
  const bf16* Kb = K + (size_t)b * S_ * E_ + (size_t)h * 64;
  const bf16* Vb = Vt + (size_t)bh * 64 * S_;

  auto stage = [&](int buf, int kt) {
#pragma unroll
    for (int op = 0; op < 2; ++op) {
      int rb = wv * 16 + op * 8;
      int cK = (sc8 ^ sr ^ ((rb >> 3) & 7)) * 8;
      gl_lds16(Kb + (size_t)(kt * 64 + rb + sr) * E_ + cK, Ks[buf] + rb * 64);
      gl_lds16(Vb + (size_t)(rb + sr) * S_ + kt * 64 + cK, Vs[buf] + rb * 64);
    }
  };

  stage(0, 0);
  __syncthreads();

  for (int kt = 0; kt < S_ / 64; ++kt) {
    const int cur = kt & 1;
    if (kt + 1 < S_ / 64) stage(cur ^ 1, kt + 1);

    // ---- QK^T: sc[ct][qt], scores S^T[k = ct*32 + crow][q = qt*32+ln] ----
    f32x16 sc[2][2] = {};
    __builtin_amdgcn_s_setprio(1);
#pragma unroll
    for (int ct = 0; ct < 2; ++ct) {
#pragma unroll
      for (int dc = 0; dc < 4; ++dc) {
        int row = ct * 32 + ln;
        int c = (dc * 2 + hi) ^ g ^ (ct * 4);
        bf16x8 kf = *(const bf16x8*)&Ks[cur][row * 64 + c * 8];
#pragma unroll
        for (int qt = 0; qt < 2; ++qt)
          sc[ct][qt] = mfma32(kf, qreg[qt][dc], sc[ct][qt]);
      }
    }
    __builtin_amdgcn_s_setprio(0);

    // ---- masks: mq[qt][ct] pre-shifted by hi*4 ----
    uint32_t pw0 = pbits[b * 64 + kt * 2], pw1 = pbits[b * 64 + kt * 2 + 1];
    uint32_t mq[2][2];
#pragma unroll
    for (int qt = 0; qt < 2; ++qt) {
      uint2 mv = *(const uint2*)(mbits + (size_t)(qw + qt * 32 + ln) * 64 + kt * 2);
      mq[qt][0] = (mv.x & pw0) >> (hi * 4);
      mq[qt][1] = (mv.y & pw1) >> (hi * 4);
    }

    // ---- softmax per qt (raw max; mask zeroes p after exp) ----
    uint32_t up[2][16];                    // packed bf16 pairs
#pragma unroll
    for (int qt = 0; qt < 2; ++qt) {
      float t0 = fmaxf(fmaxf(sc[0][qt][0], sc[0][qt][1]), fmaxf(sc[0][qt][2], sc[0][qt][3]));
#pragma unroll
      for (int r = 4; r < 16; r += 4)
        t0 = fmaxf(t0, fmaxf(fmaxf(sc[0][qt][r], sc[0][qt][r + 1]),
                             fmaxf(sc[0][qt][r + 2], sc[0][qt][r + 3])));
      float t1 = fmaxf(fmaxf(sc[1][qt][0], sc[1][qt][1]), fmaxf(sc[1][qt][2], sc[1][qt][3]));
#pragma unroll
      for (int r = 4; r < 16; r += 4)
        t1 = fmaxf(t1, fmaxf(fmaxf(sc[1][qt][r], sc[1][qt][r + 1]),
                             fmaxf(sc[1][qt][r + 2], sc[1][qt][r + 3])));
      float tmax = fmaxf(t0, t1);
      tmax = fmaxf(tmax, __shfl_xor(tmax, 32));

      if (!__all(tmax <= m_run[qt] + 10.f)) {
        float mnew = fmaxf(m_run[qt], tmax);
        float rs = __builtin_amdgcn_exp2f(m_run[qt] - mnew);
        m_run[qt] = mnew;
        l_run[qt] *= rs;
#pragma unroll
        for (int dt = 0; dt < 2; ++dt) o[dt][qt] = o[dt][qt] * rs;
      }

      float psum = 0.f;
#pragma unroll
      for (int ct = 0; ct < 2; ++ct) {
        float p[16];
#pragma unroll
        for (int r = 0; r < 16; ++r) {
          const int rel = (r & 3) + 8 * (r >> 2);   // + hi*4 already shifted out
          float pe = __builtin_amdgcn_exp2f(sc[ct][qt][r] - m_run[qt]);
          uint32_t keep = (uint32_t)(((int32_t)(mq[qt][ct] << (31 - rel))) >> 31);
          uint32_t pb = __builtin_bit_cast(uint32_t, pe) & keep;
          p[r] = __builtin_bit_cast(float, pb);
        }
#pragma unroll
        for (int r = 0; r < 16; r += 4)
          psum += (p[r] + p[r + 1]) + (p[r + 2] + p[r + 3]);
#pragma unroll
        for (int j = 0; j < 8; ++j)
          up[qt][ct * 8 + j] = cvtpk(p[2 * j], p[2 * j + 1]);
      }
      psum += __shfl_xor(psum, 32);
      l_run[qt] += psum;
    }

    // ---- PV: in-register P fragments via permlane32_swap ----
#pragma unroll
    for (int kc = 0; kc < 4; ++kc) {
      const int ct = kc >> 1, base = ct * 8 + (kc & 1) * 4;
      bf16x8 pf[2];
#pragma unroll
      for (int qt = 0; qt < 2; ++qt) {
        plswap(up[qt][base + 0], up[qt][base + 2]);
        plswap(up[qt][base + 1], up[qt][base + 3]);
        u32x4 w = {up[qt][base + 0], up[qt][base + 1], up[qt][base + 2], up[qt][base + 3]};
        pf[qt] = __builtin_bit_cast(bf16x8, w);
      }
      __builtin_amdgcn_s_setprio(1);
#pragma unroll
      for (int dt = 0; dt < 2; ++dt) {
        int row = dt * 32 + ln;
        int c = (kc * 2 + hi) ^ g ^ (dt * 4);
        bf16x8 vf = *(const bf16x8*)&Vs[cur][row * 64 + c * 8];
#pragma unroll
        for (int qt = 0; qt < 2; ++qt)
          o[dt][qt] = mfma32(vf, pf[qt], o[dt][qt]);
      }
      __builtin_amdgcn_s_setprio(0);
    }
    __syncthreads();
  }

  // ---- epilogue ----
#pragma unroll
  for (int qt = 0; qt < 2; ++qt) {
    float inv = 1.0f / l_run[qt];
    size_t qoff = (size_t)(b * S_ + qw + qt * 32 + ln) * E_ + h * 64;
#pragma unroll
    for (int dt = 0; dt < 2; ++dt) {
#pragma unroll
      for (int rg = 0; rg < 4; ++rg) {
        bf16x4 ov;
#pragma unroll
        for (int j = 0; j < 4; ++j) ov[j] = (bf16)(o[dt][qt][rg * 4 + j] * inv);
        *(bf16x4*)(alpha + qoff + dt * 32 + rg * 8 + hi * 4) = ov;
      }
    }
  }
}

// ---------------- launch ----------------
extern "C" void kernel_launch(void* const* d_in, const int* in_sizes, int n_in,
                              void* d_out, int out_size, void* d_ws, size_t ws_size,
                              hipStream_t stream) {
  const float* query = (const float*)d_in[0];
  const float* key_t = (const float*)d_in[1];
  const float* value = (const float*)d_in[2];
  const int*   mask  = (const int*)d_in[3];
  const int*   pad   = (const int*)d_in[4];
  const float* Wq    = (const float*)d_in[5];
  const float* Wk    = (const float*)d_in[6];
  const float* Wv    = (const float*)d_in[7];
  const float* Wo    = (const float*)d_in[8];

  char* ws = (char*)d_ws;
  bf16* Abuf = (bf16*)ws;
  bf16* Vt    = (bf16*)ws;
  bf16* alpha = (bf16*)(ws + ((size_t)16 << 20));
  bf16* Wb   = (bf16*)(ws + ((size_t)48 << 20));
  bf16* QKV  = (bf16*)(ws + ((size_t)56 << 20));
  uint32_t* mbits = (uint32_t*)(ws + ((size_t)104 << 20));
  uint32_t* pbits = mbits + (size_t)S_ * 64;

  const size_t AM = 8192ull * 1024ull;
  const size_t WM = 1024ull * 1024ull;

  pack_mask_kernel<<<512, 256, 0, stream>>>(mask, mbits);
  pack_pad_kernel<<<1, 256, 0, stream>>>(pad, pbits);

  cvt_act<<<dim3(4096, 1, 3), 256, 0, stream>>>(query, key_t, value, Abuf);
  const float qscale = 0.17677669529663687f;           // 1024^-0.25
  const float log2e  = 1.4426950408889634f;
  cvt_w<<<dim3(512, 1, 4), 256, 0, stream>>>(Wq, Wk, Wv, Wo, Wb, qscale * log2e, qscale);

  GA gq{Abuf,          Wb,          QKV};
  GA gk{Abuf + AM,     Wb + WM,     QKV + AM};
  GA gv{Abuf + 2 * AM, Wb + 2 * WM, QKV + 2 * AM};
  gemm_bf<false><<<dim3(64, 8, 3), 256, 0, stream>>>(gq, gk, gv);

  transpose_v<<<dim3(32, 64), 256, 0, stream>>>(QKV + 2 * AM, Vt);

  attn_kernel<<<512, 256, 0, stream>>>(QKV, QKV + AM, Vt, mbits, pbits, alpha);

  GA go{alpha, Wb + 3 * WM, d_out};
  gemm_bf<true><<<dim3(64, 8, 1), 256, 0, stream>>>(go, go, go);
}

// Round 5
// 237.229 us; speedup vs baseline: 2.4810x; 1.0881x over previous
//
#include <hip/hip_runtime.h>
#include <stdint.h>

#define B_  4
#define S_  2048
#define E_  1024
#define H_  16
#define D_  64

typedef __bf16 bf16;
typedef __bf16 bf16x4 __attribute__((ext_vector_type(4)));
typedef __bf16 bf16x8 __attribute__((ext_vector_type(8)));
typedef float  f32x4 __attribute__((ext_vector_type(4)));
typedef float  f32x16 __attribute__((ext_vector_type(16)));
typedef uint32_t u32x4 __attribute__((ext_vector_type(4)));

__device__ __forceinline__ f32x4 mfma16(bf16x8 a, bf16x8 b, f32x4 c) {
  return __builtin_amdgcn_mfma_f32_16x16x32_bf16(a, b, c, 0, 0, 0);
}
__device__ __forceinline__ f32x16 mfma32(bf16x8 a, bf16x8 b, f32x16 c) {
  return __builtin_amdgcn_mfma_f32_32x32x16_bf16(a, b, c, 0, 0, 0);
}

// GEMM swizzle (16-row frag groups): chunk ^= row&7
__device__ __forceinline__ int sw(int row, int idx) { return idx ^ ((row & 7) << 3); }

__device__ __forceinline__ void gl_lds16(const void* g, void* l) {
  __builtin_amdgcn_global_load_lds(
      (const __attribute__((address_space(1))) void*)g,
      (__attribute__((address_space(3))) void*)l, 16, 0, 0);
}

__device__ __forceinline__ uint32_t cvtpk(float lo, float hi) {
  uint32_t r;
  asm("v_cvt_pk_bf16_f32 %0, %1, %2" : "=v"(r) : "v"(lo), "v"(hi));
  return r;
}
__device__ __forceinline__ void plswap(uint32_t& a, uint32_t& b) {
  asm("v_permlane32_swap_b32 %0, %1" : "+v"(a), "+v"(b));
}

// ---------------- mask packing ----------------
__global__ void pack_mask_kernel(const int* __restrict__ mask, uint32_t* __restrict__ mbits) {
  int idx = blockIdx.x * 256 + threadIdx.x;
  int q = idx >> 6, w = idx & 63;
  const int* p = mask + q * S_ + w * 32;
  uint32_t bits = 0;
#pragma unroll
  for (int j = 0; j < 32; j += 4) {
    int4 v = *(const int4*)(p + j);
    bits |= (v.x != 0 ? 1u : 0u) << (j + 0);
    bits |= (v.y != 0 ? 1u : 0u) << (j + 1);
    bits |= (v.z != 0 ? 1u : 0u) << (j + 2);
    bits |= (v.w != 0 ? 1u : 0u) << (j + 3);
  }
  mbits[idx] = bits;
}

__global__ void pack_pad_kernel(const int* __restrict__ pad, uint32_t* __restrict__ pbits) {
  int idx = threadIdx.x;
  int b = idx >> 6, w = idx & 63;
  const int* p = pad + b * S_ + w * 32;
  uint32_t bits = 0;
#pragma unroll
  for (int j = 0; j < 32; j += 4) {
    int4 v = *(const int4*)(p + j);
    bits |= (v.x != 0 ? 1u : 0u) << (j + 0);
    bits |= (v.y != 0 ? 1u : 0u) << (j + 1);
    bits |= (v.z != 0 ? 1u : 0u) << (j + 2);
    bits |= (v.w != 0 ? 1u : 0u) << (j + 3);
  }
  pbits[idx] = bits;
}

// ---------------- fp32 -> bf16 converts ----------------
__global__ __launch_bounds__(256)
void cvt_act(const float* __restrict__ q, const float* __restrict__ k,
             const float* __restrict__ v, bf16* __restrict__ out) {
  const float* src = blockIdx.z == 0 ? q : (blockIdx.z == 1 ? k : v);
  size_t i = ((size_t)blockIdx.x * 256 + threadIdx.x) * 8;
  float4 a = *(const float4*)(src + i);
  float4 b = *(const float4*)(src + i + 4);
  bf16x8 o;
  o[0] = (bf16)a.x; o[1] = (bf16)a.y; o[2] = (bf16)a.z; o[3] = (bf16)a.w;
  o[4] = (bf16)b.x; o[5] = (bf16)b.y; o[6] = (bf16)b.z; o[7] = (bf16)b.w;
  *(bf16x8*)(out + (size_t)blockIdx.z * (8192ull * 1024ull) + i) = o;
}

__global__ __launch_bounds__(256)
void cvt_w(const float* __restrict__ w0, const float* __restrict__ w1,
           const float* __restrict__ w2, const float* __restrict__ w3,
           bf16* __restrict__ out, float sq, float sk) {
  int z = blockIdx.z;
  const float* src = z == 0 ? w0 : (z == 1 ? w1 : (z == 2 ? w2 : w3));
  float s = (z == 0) ? sq : ((z == 1) ? sk : 1.0f);
  size_t i = ((size_t)blockIdx.x * 256 + threadIdx.x) * 8;
  float4 a = *(const float4*)(src + i);
  float4 b = *(const float4*)(src + i + 4);
  bf16x8 o;
  o[0] = (bf16)(a.x * s); o[1] = (bf16)(a.y * s); o[2] = (bf16)(a.z * s); o[3] = (bf16)(a.w * s);
  o[4] = (bf16)(b.x * s); o[5] = (bf16)(b.y * s); o[6] = (bf16)(b.z * s); o[7] = (bf16)(b.w * s);
  *(bf16x8*)(out + (size_t)z * (1024ull * 1024ull) + i) = o;
}

// ---------------- GEMM: C = A @ W^T (m97-style) ----------------
struct GA { const bf16* A; const bf16* W; void* O; };

template<bool OUT_F32>
__global__ __launch_bounds__(256, 2)
void gemm_bf(GA g0, GA g1, GA g2) {
  GA g = (blockIdx.z == 0) ? g0 : ((blockIdx.z == 1) ? g1 : g2);
  const int tid = threadIdx.x;
  const int l = tid & 63, wv = tid >> 6;
  const int lg = l >> 4, lr = l & 15;
  const int wr = wv >> 1, wc = wv & 1;
  const int brow = blockIdx.x * 128, bcol = blockIdx.y * 128;
  const int sr = l >> 3, sc8 = l & 7;

  __shared__ bf16 As[128 * 64];
  __shared__ bf16 Bs[128 * 64];

  f32x4 acc[4][4] = {};

  const bf16* Ab = g.A + (size_t)(brow + wv * 32 + sr) * E_ + (size_t)(sc8 ^ sr) * 8;
  const bf16* Bb = g.W + (size_t)(bcol + wv * 32 + sr) * E_ + (size_t)(sc8 ^ sr) * 8;
  bf16* la = As + (wv * 32) * 64;
  bf16* lb = Bs + (wv * 32) * 64;

  for (int kt = 0; kt < E_ / 64; ++kt) {
    __syncthreads();
    const bf16* a = Ab + kt * 64;
    const bf16* b = Bb + kt * 64;
#pragma unroll
    for (int i = 0; i < 4; ++i) {
      gl_lds16(a + (size_t)i * 8 * E_, la + i * 8 * 64);
      gl_lds16(b + (size_t)i * 8 * E_, lb + i * 8 * 64);
    }
    __syncthreads();
#pragma unroll
    for (int kk = 0; kk < 2; ++kk) {
      bf16x8 af[4], bfr[4];
#pragma unroll
      for (int ms = 0; ms < 4; ++ms) {
        int row = wr * 64 + ms * 16 + lr;
        af[ms] = *(const bf16x8*)&As[sw(row, row * 64 + kk * 32 + lg * 8)];
      }
#pragma unroll
      for (int ns = 0; ns < 4; ++ns) {
        int row = wc * 64 + ns * 16 + lr;
        bfr[ns] = *(const bf16x8*)&Bs[sw(row, row * 64 + kk * 32 + lg * 8)];
      }
#pragma unroll
      for (int ms = 0; ms < 4; ++ms)
#pragma unroll
        for (int ns = 0; ns < 4; ++ns)
          acc[ms][ns] = mfma16(af[ms], bfr[ns], acc[ms][ns]);
    }
  }
#pragma unroll
  for (int ms = 0; ms < 4; ++ms) {
#pragma unroll
    for (int ns = 0; ns < 4; ++ns) {
#pragma unroll
      for (int r = 0; r < 4; ++r) {
        int row = brow + wr * 64 + ms * 16 + lg * 4 + r;
        int col = bcol + wc * 64 + ns * 16 + lr;
        if constexpr (OUT_F32) ((float*)g.O)[(size_t)row * E_ + col] = acc[ms][ns][r];
        else                   ((bf16*)g.O)[(size_t)row * E_ + col] = (bf16)acc[ms][ns][r];
      }
    }
  }
}

// ---------------- V transpose ----------------
__global__ __launch_bounds__(256, 2)
void transpose_v(const bf16* __restrict__ V, bf16* __restrict__ Vt) {
  int bh = blockIdx.y; int b = bh >> 4, h = bh & 15;
  int s0 = blockIdx.x * 64;
  int tid = threadIdx.x;
  __shared__ bf16 t[64][72];
  int rb = tid >> 3, seg = tid & 7;
#pragma unroll
  for (int i = 0; i < 2; ++i) {
    int row = rb + 32 * i;
    bf16x8 v = *(const bf16x8*)(V + (size_t)(b * S_ + s0 + row) * E_ + h * 64 + seg * 8);
#pragma unroll
    for (int j = 0; j < 8; ++j) t[row][seg * 8 + j] = v[j];
  }
  __syncthreads();
#pragma unroll
  for (int i = 0; i < 2; ++i) {
    int d = rb + 32 * i;
    bf16x8 v;
#pragma unroll
    for (int j = 0; j < 8; ++j) v[j] = t[seg * 8 + j][d];
    *(bf16x8*)(Vt + ((size_t)bh * 64 + d) * S_ + s0 + seg * 8) = v;
  }
}

// ---------------- flash attention: no-max softmax, MFMA row-sums ----------------
// grid(512): raw -> xcd=raw&7 owns bh in [xcd*8, xcd*8+8)
__global__ __launch_bounds__(256, 2)
void attn_kernel(const bf16* __restrict__ Q, const bf16* __restrict__ K,
                 const bf16* __restrict__ Vt, const uint32_t* __restrict__ mbits,
                 const uint32_t* __restrict__ pbits, bf16* __restrict__ alpha) {
  const int raw = blockIdx.x;
  const int xcd = raw & 7, slot = raw >> 3;
  const int bh = xcd * 8 + (slot >> 3), qblk = slot & 7;
  const int b = bh >> 4, h = bh & 15;
  const int tid = threadIdx.x, wv = tid >> 6, l = tid & 63;
  const int ln = l & 31, hi = l >> 5;
  const int qw = qblk * 256 + wv * 64;
  const int sr = l >> 3, sc8 = l & 7;
  const int g = (ln & 7) ^ (ln >> 3);      // read-side row-hash

  __shared__ bf16 Ks[2][64 * 64];          // [k][d], swizzled chunks
  __shared__ bf16 Vs[2][64 * 64];          // [d][k], swizzled chunks

  // Q fragments in registers: qreg[qt][dc] = Q[qw+qt*32+ln][dc*16+hi*8 ..+8]
  bf16x8 qreg[2][4];
#pragma unroll
  for (int qt = 0; qt < 2; ++qt)
#pragma unroll
    for (int dc = 0; dc < 4; ++dc)
      qreg[qt][dc] = *(const bf16x8*)(Q + (size_t)(b * S_ + qw + qt * 32 + ln) * E_
                                        + h * 64 + dc * 16 + hi * 8);

  bf16x8 ones;
#pragma unroll
  for (int j = 0; j < 8; ++j) ones[j] = (bf16)1.0f;

  f32x16 o[2][2] = {};                     // o[dt][qt]
  f32x16 lacc[2] = {};                     // row-sums of P (all regs equal)

  const bf16* Kb = K + (size_t)b * S_ * E_ + (size_t)h * 64;
  const bf16* Vb = Vt + (size_t)bh * 64 * S_;

  auto stage = [&](int buf, int kt) {
#pragma unroll
    for (int op = 0; op < 2; ++op) {
      int rb = wv * 16 + op * 8;
      int cK = (sc8 ^ sr ^ ((rb >> 3) & 7)) * 8;
      gl_lds16(Kb + (size_t)(kt * 64 + rb + sr) * E_ + cK, Ks[buf] + rb * 64);
      gl_lds16(Vb + (size_t)(rb + sr) * S_ + kt * 64 + cK, Vs[buf] + rb * 64);
    }
  };

  stage(0, 0);
  __syncthreads();

  for (int kt = 0; kt < S_ / 64; ++kt) {
    const int cur = kt & 1;
    if (kt + 1 < S_ / 64) stage(cur ^ 1, kt + 1);

    // ---- QK^T: sc[ct][qt] = S^T[k = kt*64+ct*32+crow][q = qw+qt*32+ln] ----
    f32x16 sc[2][2] = {};
    __builtin_amdgcn_s_setprio(1);
#pragma unroll
    for (int ct = 0; ct < 2; ++ct) {
#pragma unroll
      for (int dc = 0; dc < 4; ++dc) {
        int row = ct * 32 + ln;
        int c = (dc * 2 + hi) ^ g ^ (ct * 4);
        bf16x8 kf = *(const bf16x8*)&Ks[cur][row * 64 + c * 8];
#pragma unroll
        for (int qt = 0; qt < 2; ++qt)
          sc[ct][qt] = mfma32(kf, qreg[qt][dc], sc[ct][qt]);
      }
    }
    __builtin_amdgcn_s_setprio(0);

    // ---- masks: mq[qt][ct] pre-shifted by hi*4 ----
    uint32_t pw0 = pbits[b * 64 + kt * 2], pw1 = pbits[b * 64 + kt * 2 + 1];
    uint32_t mq[2][2];
#pragma unroll
    for (int qt = 0; qt < 2; ++qt) {
      uint2 mv = *(const uint2*)(mbits + (size_t)(qw + qt * 32 + ln) * 64 + kt * 2);
      mq[qt][0] = (mv.x & pw0) >> (hi * 4);
      mq[qt][1] = (mv.y & pw1) >> (hi * 4);
    }

    // ---- p = exp2(s) (no max subtraction), masked via sbfe+and; pack to bf16 ----
    uint32_t up[2][16];
#pragma unroll
    for (int qt = 0; qt < 2; ++qt) {
#pragma unroll
      for (int ct = 0; ct < 2; ++ct) {
        float p[16];
#pragma unroll
        for (int r = 0; r < 16; ++r) {
          const int rel = (r & 3) + 8 * (r >> 2);
          float pe = __builtin_amdgcn_exp2f(sc[ct][qt][r]);
          uint32_t keep = (uint32_t)__builtin_amdgcn_sbfe(mq[qt][ct], rel, 1);
          p[r] = __builtin_bit_cast(float, __builtin_bit_cast(uint32_t, pe) & keep);
        }
#pragma unroll
        for (int j = 0; j < 8; ++j)
          up[qt][ct * 8 + j] = cvtpk(p[2 * j], p[2 * j + 1]);
      }
    }

    // ---- PV + l-sums: in-register P fragments via permlane32_swap ----
#pragma unroll
    for (int kc = 0; kc < 4; ++kc) {
      const int ct = kc >> 1, base = ct * 8 + (kc & 1) * 4;
      bf16x8 pf[2];
#pragma unroll
      for (int qt = 0; qt < 2; ++qt) {
        plswap(up[qt][base + 0], up[qt][base + 2]);
        plswap(up[qt][base + 1], up[qt][base + 3]);
        u32x4 w = {up[qt][base + 0], up[qt][base + 1], up[qt][base + 2], up[qt][base + 3]};
        pf[qt] = __builtin_bit_cast(bf16x8, w);
      }
      __builtin_amdgcn_s_setprio(1);
#pragma unroll
      for (int dt = 0; dt < 2; ++dt) {
        int row = dt * 32 + ln;
        int c = (kc * 2 + hi) ^ g ^ (dt * 4);
        bf16x8 vf = *(const bf16x8*)&Vs[cur][row * 64 + c * 8];
#pragma unroll
        for (int qt = 0; qt < 2; ++qt)
          o[dt][qt] = mfma32(vf, pf[qt], o[dt][qt]);
      }
#pragma unroll
      for (int qt = 0; qt < 2; ++qt)
        lacc[qt] = mfma32(ones, pf[qt], lacc[qt]);
      __builtin_amdgcn_s_setprio(0);
    }
    __syncthreads();
  }

  // ---- epilogue: alpha = o / l  (l = lacc[qt][0], identical across regs) ----
#pragma unroll
  for (int qt = 0; qt < 2; ++qt) {
    float inv = 1.0f / lacc[qt][0];
    size_t qoff = (size_t)(b * S_ + qw + qt * 32 + ln) * E_ + h * 64;
#pragma unroll
    for (int dt = 0; dt < 2; ++dt) {
#pragma unroll
      for (int rg = 0; rg < 4; ++rg) {
        bf16x4 ov;
#pragma unroll
        for (int j = 0; j < 4; ++j) ov[j] = (bf16)(o[dt][qt][rg * 4 + j] * inv);
        *(bf16x4*)(alpha + qoff + dt * 32 + rg * 8 + hi * 4) = ov;
      }
    }
  }
}

// ---------------- launch ----------------
extern "C" void kernel_launch(void* const* d_in, const int* in_sizes, int n_in,
                              void* d_out, int out_size, void* d_ws, size_t ws_size,
                              hipStream_t stream) {
  const float* query = (const float*)d_in[0];
  const float* key_t = (const float*)d_in[1];
  const float* value = (const float*)d_in[2];
  const int*   mask  = (const int*)d_in[3];
  const int*   pad   = (const int*)d_in[4];
  const float* Wq    = (const float*)d_in[5];
  const float* Wk    = (const float*)d_in[6];
  const float* Wv    = (const float*)d_in[7];
  const float* Wo    = (const float*)d_in[8];

  char* ws = (char*)d_ws;
  bf16* Abuf = (bf16*)ws;
  bf16* Vt    = (bf16*)ws;
  bf16* alpha = (bf16*)(ws + ((size_t)16 << 20));
  bf16* Wb   = (bf16*)(ws + ((size_t)48 << 20));
  bf16* QKV  = (bf16*)(ws + ((size_t)56 << 20));
  uint32_t* mbits = (uint32_t*)(ws + ((size_t)104 << 20));
  uint32_t* pbits = mbits + (size_t)S_ * 64;

  const size_t AM = 8192ull * 1024ull;
  const size_t WM = 1024ull * 1024ull;

  pack_mask_kernel<<<512, 256, 0, stream>>>(mask, mbits);
  pack_pad_kernel<<<1, 256, 0, stream>>>(pad, pbits);

  cvt_act<<<dim3(4096, 1, 3), 256, 0, stream>>>(query, key_t, value, Abuf);
  const float qscale = 0.17677669529663687f;           // 1024^-0.25
  const float log2e  = 1.4426950408889634f;
  cvt_w<<<dim3(512, 1, 4), 256, 0, stream>>>(Wq, Wk, Wv, Wo, Wb, qscale * log2e, qscale);

  GA gq{Abuf,          Wb,          QKV};
  GA gk{Abuf + AM,     Wb + WM,     QKV + AM};
  GA gv{Abuf + 2 * AM, Wb + 2 * WM, QKV + 2 * AM};
  gemm_bf<false><<<dim3(64, 8, 3), 256, 0, stream>>>(gq, gk, gv);

  transpose_v<<<dim3(32, 64), 256, 0, stream>>>(QKV + 2 * AM, Vt);

  attn_kernel<<<512, 256, 0, stream>>>(QKV, QKV + AM, Vt, mbits, pbits, alpha);

  GA go{alpha, Wb + 3 * WM, d_out};
  gemm_bf<true><<<dim3(64, 8, 1), 256, 0, stream>>>(go, go, go);
}

// Round 6
// 222.941 us; speedup vs baseline: 2.6400x; 1.0641x over previous
//
#include <hip/hip_runtime.h>
#include <stdint.h>

#define B_  4
#define S_  2048
#define E_  1024
#define H_  16
#define D_  64

typedef __bf16 bf16;
typedef __bf16 bf16x4 __attribute__((ext_vector_type(4)));
typedef __bf16 bf16x8 __attribute__((ext_vector_type(8)));
typedef float  f32x4 __attribute__((ext_vector_type(4)));
typedef float  f32x16 __attribute__((ext_vector_type(16)));
typedef uint32_t u32x4 __attribute__((ext_vector_type(4)));

__device__ __forceinline__ f32x4 mfma16(bf16x8 a, bf16x8 b, f32x4 c) {
  return __builtin_amdgcn_mfma_f32_16x16x32_bf16(a, b, c, 0, 0, 0);
}
__device__ __forceinline__ f32x16 mfma32(bf16x8 a, bf16x8 b, f32x16 c) {
  return __builtin_amdgcn_mfma_f32_32x32x16_bf16(a, b, c, 0, 0, 0);
}

// GEMM swizzle (16-row frag groups): chunk ^= row&7
__device__ __forceinline__ int sw(int row, int idx) { return idx ^ ((row & 7) << 3); }

__device__ __forceinline__ void gl_lds16(const void* g, void* l) {
  __builtin_amdgcn_global_load_lds(
      (const __attribute__((address_space(1))) void*)g,
      (__attribute__((address_space(3))) void*)l, 16, 0, 0);
}

__device__ __forceinline__ uint32_t cvtpk(float lo, float hi) {
  uint32_t r;
  asm("v_cvt_pk_bf16_f32 %0, %1, %2" : "=v"(r) : "v"(lo), "v"(hi));
  return r;
}
__device__ __forceinline__ void plswap(uint32_t& a, uint32_t& b) {
  asm("v_permlane32_swap_b32 %0, %1" : "+v"(a), "+v"(b));
}

// ---------------- mask packing ----------------
__global__ void pack_mask_kernel(const int* __restrict__ mask, uint32_t* __restrict__ mbits) {
  int idx = blockIdx.x * 256 + threadIdx.x;
  int q = idx >> 6, w = idx & 63;
  const int* p = mask + q * S_ + w * 32;
  uint32_t bits = 0;
#pragma unroll
  for (int j = 0; j < 32; j += 4) {
    int4 v = *(const int4*)(p + j);
    bits |= (v.x != 0 ? 1u : 0u) << (j + 0);
    bits |= (v.y != 0 ? 1u : 0u) << (j + 1);
    bits |= (v.z != 0 ? 1u : 0u) << (j + 2);
    bits |= (v.w != 0 ? 1u : 0u) << (j + 3);
  }
  mbits[idx] = bits;
}

__global__ void pack_pad_kernel(const int* __restrict__ pad, uint32_t* __restrict__ pbits) {
  int idx = threadIdx.x;
  int b = idx >> 6, w = idx & 63;
  const int* p = pad + b * S_ + w * 32;
  uint32_t bits = 0;
#pragma unroll
  for (int j = 0; j < 32; j += 4) {
    int4 v = *(const int4*)(p + j);
    bits |= (v.x != 0 ? 1u : 0u) << (j + 0);
    bits |= (v.y != 0 ? 1u : 0u) << (j + 1);
    bits |= (v.z != 0 ? 1u : 0u) << (j + 2);
    bits |= (v.w != 0 ? 1u : 0u) << (j + 3);
  }
  pbits[idx] = bits;
}

// ---------------- fp32 -> bf16 converts ----------------
__global__ __launch_bounds__(256)
void cvt_act(const float* __restrict__ q, const float* __restrict__ k,
             const float* __restrict__ v, bf16* __restrict__ out) {
  const float* src = blockIdx.z == 0 ? q : (blockIdx.z == 1 ? k : v);
  size_t i = ((size_t)blockIdx.x * 256 + threadIdx.x) * 8;
  float4 a = *(const float4*)(src + i);
  float4 b = *(const float4*)(src + i + 4);
  bf16x8 o;
  o[0] = (bf16)a.x; o[1] = (bf16)a.y; o[2] = (bf16)a.z; o[3] = (bf16)a.w;
  o[4] = (bf16)b.x; o[5] = (bf16)b.y; o[6] = (bf16)b.z; o[7] = (bf16)b.w;
  *(bf16x8*)(out + (size_t)blockIdx.z * (8192ull * 1024ull) + i) = o;
}

__global__ __launch_bounds__(256)
void cvt_w(const float* __restrict__ w0, const float* __restrict__ w1,
           const float* __restrict__ w2, const float* __restrict__ w3,
           bf16* __restrict__ out, float sq, float sk) {
  int z = blockIdx.z;
  const float* src = z == 0 ? w0 : (z == 1 ? w1 : (z == 2 ? w2 : w3));
  float s = (z == 0) ? sq : ((z == 1) ? sk : 1.0f);
  size_t i = ((size_t)blockIdx.x * 256 + threadIdx.x) * 8;
  float4 a = *(const float4*)(src + i);
  float4 b = *(const float4*)(src + i + 4);
  bf16x8 o;
  o[0] = (bf16)(a.x * s); o[1] = (bf16)(a.y * s); o[2] = (bf16)(a.z * s); o[3] = (bf16)(a.w * s);
  o[4] = (bf16)(b.x * s); o[5] = (bf16)(b.y * s); o[6] = (bf16)(b.z * s); o[7] = (bf16)(b.w * s);
  *(bf16x8*)(out + (size_t)z * (1024ull * 1024ull) + i) = o;
}

// ---------------- GEMM: C = A @ W^T (m97-style); z==2 writes V transposed ----------------
struct GA { const bf16* A; const bf16* W; void* O; };

template<bool OUT_F32>
__global__ __launch_bounds__(256, 2)
void gemm_bf(GA g0, GA g1, GA g2) {
  GA g = (blockIdx.z == 0) ? g0 : ((blockIdx.z == 1) ? g1 : g2);
  const int tid = threadIdx.x;
  const int l = tid & 63, wv = tid >> 6;
  const int lg = l >> 4, lr = l & 15;
  const int wr = wv >> 1, wc = wv & 1;
  const int brow = blockIdx.x * 128, bcol = blockIdx.y * 128;
  const int sr = l >> 3, sc8 = l & 7;

  __shared__ bf16 Ls[2][128 * 64];   // As | Bs (contiguous for transpose reuse)
  bf16* As = Ls[0];
  bf16* Bs = Ls[1];

  f32x4 acc[4][4] = {};

  const bf16* Ab = g.A + (size_t)(brow + wv * 32 + sr) * E_ + (size_t)(sc8 ^ sr) * 8;
  const bf16* Bb = g.W + (size_t)(bcol + wv * 32 + sr) * E_ + (size_t)(sc8 ^ sr) * 8;
  bf16* la = As + (wv * 32) * 64;
  bf16* lb = Bs + (wv * 32) * 64;

  for (int kt = 0; kt < E_ / 64; ++kt) {
    __syncthreads();
    const bf16* a = Ab + kt * 64;
    const bf16* b = Bb + kt * 64;
#pragma unroll
    for (int i = 0; i < 4; ++i) {
      gl_lds16(a + (size_t)i * 8 * E_, la + i * 8 * 64);
      gl_lds16(b + (size_t)i * 8 * E_, lb + i * 8 * 64);
    }
    __syncthreads();
#pragma unroll
    for (int kk = 0; kk < 2; ++kk) {
      bf16x8 af[4], bfr[4];
#pragma unroll
      for (int ms = 0; ms < 4; ++ms) {
        int row = wr * 64 + ms * 16 + lr;
        af[ms] = *(const bf16x8*)&As[sw(row, row * 64 + kk * 32 + lg * 8)];
      }
#pragma unroll
      for (int ns = 0; ns < 4; ++ns) {
        int row = wc * 64 + ns * 16 + lr;
        bfr[ns] = *(const bf16x8*)&Bs[sw(row, row * 64 + kk * 32 + lg * 8)];
      }
#pragma unroll
      for (int ms = 0; ms < 4; ++ms)
#pragma unroll
        for (int ns = 0; ns < 4; ++ns)
          acc[ms][ns] = mfma16(af[ms], bfr[ns], acc[ms][ns]);
    }
  }

  if (!OUT_F32 && blockIdx.z == 2) {
    // ---- V epilogue: transpose 128x128 tile via LDS -> Vt[bh][d][s] ----
    bf16* T = &Ls[0][0];               // 128 x 128 bf16 = 32 KB
    __syncthreads();                   // done reading As/Bs
#pragma unroll
    for (int ms = 0; ms < 4; ++ms) {
#pragma unroll
      for (int ns = 0; ns < 4; ++ns) {
        int col = wc * 64 + ns * 16 + lr;                 // E-dim (d)
        int rowb = wr * 64 + ms * 16 + lg * 4;            // s-dim
        bf16x4 hv;
#pragma unroll
        for (int r = 0; r < 4; ++r) hv[r] = (bf16)acc[ms][ns][r];
        *(bf16x4*)&T[col * 128 + (rowb ^ ((col & 7) << 3))] = hv;
      }
    }
    __syncthreads();
    int chunk = tid & 15, dl0 = tid >> 4;
#pragma unroll
    for (int pass = 0; pass < 8; ++pass) {
      int dl = pass * 16 + dl0;
      bf16x8 v = *(const bf16x8*)&T[dl * 128 + ((chunk * 8) ^ ((dl & 7) << 3))];
      int colg = bcol + dl;
      int bh2 = (brow >> 11) * 16 + (colg >> 6);
      int d = colg & 63;
      int s0 = (brow & 2047) + chunk * 8;
      *(bf16x8*)((bf16*)g.O + ((size_t)bh2 * 64 + d) * (size_t)S_ + s0) = v;
    }
    return;
  }

#pragma unroll
  for (int ms = 0; ms < 4; ++ms) {
#pragma unroll
    for (int ns = 0; ns < 4; ++ns) {
#pragma unroll
      for (int r = 0; r < 4; ++r) {
        int row = brow + wr * 64 + ms * 16 + lg * 4 + r;
        int col = bcol + wc * 64 + ns * 16 + lr;
        if constexpr (OUT_F32) ((float*)g.O)[(size_t)row * E_ + col] = acc[ms][ns][r];
        else                   ((bf16*)g.O)[(size_t)row * E_ + col] = (bf16)acc[ms][ns][r];
      }
    }
  }
}

// ---------------- flash attention: 32q/wave, QBLK=128, grid 1024 ----------------
// grid(1024): raw -> xcd=raw&7; bh = xcd*8 + (slot>>4); qblk = slot&15
__global__ __launch_bounds__(256, 4)
void attn_kernel(const bf16* __restrict__ Q, const bf16* __restrict__ K,
                 const bf16* __restrict__ Vt, const uint32_t* __restrict__ mbits,
                 const uint32_t* __restrict__ pbits, bf16* __restrict__ alpha) {
  const int raw = blockIdx.x;
  const int xcd = raw & 7, slot = raw >> 3;
  const int bh = xcd * 8 + (slot >> 4), qblk = slot & 15;
  const int b = bh >> 4, h = bh & 15;
  const int tid = threadIdx.x, wv = tid >> 6, l = tid & 63;
  const int ln = l & 31, hi = l >> 5;
  const int qw = qblk * 128 + wv * 32;
  const int sr = l >> 3, sc8 = l & 7;
  const int g = (ln & 7) ^ (ln >> 3);      // read-side row-hash

  __shared__ bf16 Ks[2][64 * 64];          // [k][d], swizzled chunks
  __shared__ bf16 Vs[2][64 * 64];          // [d][k], swizzled chunks

  // Q fragments: qreg[dc] = Q[qw+ln][dc*16+hi*8 ..+8]
  bf16x8 qreg[4];
#pragma unroll
  for (int dc = 0; dc < 4; ++dc)
    qreg[dc] = *(const bf16x8*)(Q + (size_t)(b * S_ + qw + ln) * E_ + h * 64 + dc * 16 + hi * 8);

  bf16x8 ones;
#pragma unroll
  for (int j = 0; j < 8; ++j) ones[j] = (bf16)1.0f;

  f32x16 o[2] = {};                        // o[dt]
  f32x16 lacc = {};                        // row-sums of P

  const bf16* Kb = K + (size_t)b * S_ * E_ + (size_t)h * 64;
  const bf16* Vb = Vt + (size_t)bh * 64 * S_;

  auto stage = [&](int buf, int kt) {
#pragma unroll
    for (int op = 0; op < 2; ++op) {
      int rb = wv * 16 + op * 8;
      int cK = (sc8 ^ sr ^ ((rb >> 3) & 7)) * 8;
      gl_lds16(Kb + (size_t)(kt * 64 + rb + sr) * E_ + cK, Ks[buf] + rb * 64);
      gl_lds16(Vb + (size_t)(rb + sr) * S_ + kt * 64 + cK, Vs[buf] + rb * 64);
    }
  };

  stage(0, 0);
  __syncthreads();

  for (int kt = 0; kt < S_ / 64; ++kt) {
    const int cur = kt & 1;
    if (kt + 1 < S_ / 64) stage(cur ^ 1, kt + 1);

    // ---- QK^T: sc[ct] = S^T[k = kt*64+ct*32+crow][q = qw+ln] ----
    f32x16 sc[2] = {};
    __builtin_amdgcn_s_setprio(1);
#pragma unroll
    for (int ct = 0; ct < 2; ++ct) {
#pragma unroll
      for (int dc = 0; dc < 4; ++dc) {
        int row = ct * 32 + ln;
        int c = (dc * 2 + hi) ^ g ^ (ct * 4);
        bf16x8 kf = *(const bf16x8*)&Ks[cur][row * 64 + c * 8];
        sc[ct] = mfma32(kf, qreg[dc], sc[ct]);
      }
    }
    __builtin_amdgcn_s_setprio(0);

    // ---- masks pre-shifted by hi*4 ----
    uint32_t pw0 = pbits[b * 64 + kt * 2], pw1 = pbits[b * 64 + kt * 2 + 1];
    uint2 mv = *(const uint2*)(mbits + (size_t)(qw + ln) * 64 + kt * 2);
    uint32_t mq[2];
    mq[0] = (mv.x & pw0) >> (hi * 4);
    mq[1] = (mv.y & pw1) >> (hi * 4);

    // ---- p = exp2(s), masked via sbfe+and; pack to bf16 ----
    uint32_t up[16];
#pragma unroll
    for (int ct = 0; ct < 2; ++ct) {
      float p[16];
#pragma unroll
      for (int r = 0; r < 16; ++r) {
        const int rel = (r & 3) + 8 * (r >> 2);
        float pe = __builtin_amdgcn_exp2f(sc[ct][r]);
        uint32_t keep = (uint32_t)__builtin_amdgcn_sbfe(mq[ct], rel, 1);
        p[r] = __builtin_bit_cast(float, __builtin_bit_cast(uint32_t, pe) & keep);
      }
#pragma unroll
      for (int j = 0; j < 8; ++j)
        up[ct * 8 + j] = cvtpk(p[2 * j], p[2 * j + 1]);
    }

    // ---- PV + l-sum via permlane32_swap fragments ----
#pragma unroll
    for (int kc = 0; kc < 4; ++kc) {
      const int ct = kc >> 1, base = ct * 8 + (kc & 1) * 4;
      plswap(up[base + 0], up[base + 2]);
      plswap(up[base + 1], up[base + 3]);
      u32x4 w = {up[base + 0], up[base + 1], up[base + 2], up[base + 3]};
      bf16x8 pf = __builtin_bit_cast(bf16x8, w);
      __builtin_amdgcn_s_setprio(1);
#pragma unroll
      for (int dt = 0; dt < 2; ++dt) {
        int row = dt * 32 + ln;
        int c = (kc * 2 + hi) ^ g ^ (dt * 4);
        bf16x8 vf = *(const bf16x8*)&Vs[cur][row * 64 + c * 8];
        o[dt] = mfma32(vf, pf, o[dt]);
      }
      lacc = mfma32(ones, pf, lacc);
      __builtin_amdgcn_s_setprio(0);
    }
    __syncthreads();
  }

  // ---- epilogue: alpha = o / l ----
  float inv = 1.0f / lacc[0];
  size_t qoff = (size_t)(b * S_ + qw + ln) * E_ + h * 64;
#pragma unroll
  for (int dt = 0; dt < 2; ++dt) {
#pragma unroll
    for (int rg = 0; rg < 4; ++rg) {
      bf16x4 ov;
#pragma unroll
      for (int j = 0; j < 4; ++j) ov[j] = (bf16)(o[dt][rg * 4 + j] * inv);
      *(bf16x4*)(alpha + qoff + dt * 32 + rg * 8 + hi * 4) = ov;
    }
  }
}

// ---------------- launch ----------------
extern "C" void kernel_launch(void* const* d_in, const int* in_sizes, int n_in,
                              void* d_out, int out_size, void* d_ws, size_t ws_size,
                              hipStream_t stream) {
  const float* query = (const float*)d_in[0];
  const float* key_t = (const float*)d_in[1];
  const float* value = (const float*)d_in[2];
  const int*   mask  = (const int*)d_in[3];
  const int*   pad   = (const int*)d_in[4];
  const float* Wq    = (const float*)d_in[5];
  const float* Wk    = (const float*)d_in[6];
  const float* Wv    = (const float*)d_in[7];
  const float* Wo    = (const float*)d_in[8];

  char* ws = (char*)d_ws;
  bf16* Abuf  = (bf16*)ws;                             // 48M activations (bf16)
  bf16* alpha = (bf16*)(ws + ((size_t)16 << 20));      // reuses Abuf after QKV gemm
  bf16* Wb    = (bf16*)(ws + ((size_t)48 << 20));      // 8M weights
  bf16* QKV   = (bf16*)(ws + ((size_t)56 << 20));      // Q, K at +0, +16M
  uint32_t* mbits = (uint32_t*)(ws + ((size_t)104 << 20));
  uint32_t* pbits = mbits + (size_t)S_ * 64;

  const size_t AM = 8192ull * 1024ull;
  const size_t WM = 1024ull * 1024ull;
  bf16* Vt = QKV + 2 * AM;                             // V written transposed here

  pack_mask_kernel<<<512, 256, 0, stream>>>(mask, mbits);
  pack_pad_kernel<<<1, 256, 0, stream>>>(pad, pbits);

  cvt_act<<<dim3(4096, 1, 3), 256, 0, stream>>>(query, key_t, value, Abuf);
  const float qscale = 0.17677669529663687f;           // 1024^-0.25
  const float log2e  = 1.4426950408889634f;
  cvt_w<<<dim3(512, 1, 4), 256, 0, stream>>>(Wq, Wk, Wv, Wo, Wb, qscale * log2e, qscale);

  GA gq{Abuf,          Wb,          QKV};
  GA gk{Abuf + AM,     Wb + WM,     QKV + AM};
  GA gv{Abuf + 2 * AM, Wb + 2 * WM, Vt};
  gemm_bf<false><<<dim3(64, 8, 3), 256, 0, stream>>>(gq, gk, gv);

  attn_kernel<<<1024, 256, 0, stream>>>(QKV, QKV + AM, Vt, mbits, pbits, alpha);

  GA go{alpha, Wb + 3 * WM, d_out};
  gemm_bf<true><<<dim3(64, 8, 1), 256, 0, stream>>>(go, go, go);
}

// Round 7
// 222.593 us; speedup vs baseline: 2.6441x; 1.0016x over previous
//
#include <hip/hip_runtime.h>
#include <stdint.h>

#define B_  4
#define S_  2048
#define E_  1024
#define H_  16
#define D_  64

typedef __bf16 bf16;
typedef __bf16 bf16x4 __attribute__((ext_vector_type(4)));
typedef __bf16 bf16x8 __attribute__((ext_vector_type(8)));
typedef float  f32x4 __attribute__((ext_vector_type(4)));
typedef float  f32x16 __attribute__((ext_vector_type(16)));
typedef uint32_t u32x4 __attribute__((ext_vector_type(4)));

__device__ __forceinline__ f32x4 mfma16(bf16x8 a, bf16x8 b, f32x4 c) {
  return __builtin_amdgcn_mfma_f32_16x16x32_bf16(a, b, c, 0, 0, 0);
}
__device__ __forceinline__ f32x16 mfma32(bf16x8 a, bf16x8 b, f32x16 c) {
  return __builtin_amdgcn_mfma_f32_32x32x16_bf16(a, b, c, 0, 0, 0);
}

// GEMM swizzle (16-row frag groups): chunk ^= row&7
__device__ __forceinline__ int sw(int row, int idx) { return idx ^ ((row & 7) << 3); }

__device__ __forceinline__ void gl_lds16(const void* g, void* l) {
  __builtin_amdgcn_global_load_lds(
      (const __attribute__((address_space(1))) void*)g,
      (__attribute__((address_space(3))) void*)l, 16, 0, 0);
}

__device__ __forceinline__ uint32_t cvtpk(float lo, float hi) {
  uint32_t r;
  asm("v_cvt_pk_bf16_f32 %0, %1, %2" : "=v"(r) : "v"(lo), "v"(hi));
  return r;
}
__device__ __forceinline__ void plswap(uint32_t& a, uint32_t& b) {
  asm("v_permlane32_swap_b32 %0, %1" : "+v"(a), "+v"(b));
}

// ---------------- mask packing ----------------
__global__ void pack_mask_kernel(const int* __restrict__ mask, uint32_t* __restrict__ mbits) {
  int idx = blockIdx.x * 256 + threadIdx.x;
  int q = idx >> 6, w = idx & 63;
  const int* p = mask + q * S_ + w * 32;
  uint32_t bits = 0;
#pragma unroll
  for (int j = 0; j < 32; j += 4) {
    int4 v = *(const int4*)(p + j);
    bits |= (v.x != 0 ? 1u : 0u) << (j + 0);
    bits |= (v.y != 0 ? 1u : 0u) << (j + 1);
    bits |= (v.z != 0 ? 1u : 0u) << (j + 2);
    bits |= (v.w != 0 ? 1u : 0u) << (j + 3);
  }
  mbits[idx] = bits;
}

__global__ void pack_pad_kernel(const int* __restrict__ pad, uint32_t* __restrict__ pbits) {
  int idx = threadIdx.x;
  int b = idx >> 6, w = idx & 63;
  const int* p = pad + b * S_ + w * 32;
  uint32_t bits = 0;
#pragma unroll
  for (int j = 0; j < 32; j += 4) {
    int4 v = *(const int4*)(p + j);
    bits |= (v.x != 0 ? 1u : 0u) << (j + 0);
    bits |= (v.y != 0 ? 1u : 0u) << (j + 1);
    bits |= (v.z != 0 ? 1u : 0u) << (j + 2);
    bits |= (v.w != 0 ? 1u : 0u) << (j + 3);
  }
  pbits[idx] = bits;
}

// transpose + pre-AND pad: mbt[b][kt][q] = {mbits[q][2kt]&pad, mbits[q][2kt+1]&pad}
__global__ __launch_bounds__(256)
void expand_mask(const uint32_t* __restrict__ mbits, const uint32_t* __restrict__ pbits,
                 uint2* __restrict__ mbt) {
  int idx = blockIdx.x * 256 + threadIdx.x;   // b(4) x kt(32) x q(2048)
  int q = idx & 2047;
  int kt = (idx >> 11) & 31;
  int b = idx >> 16;
  uint2 r;
  r.x = mbits[q * 64 + kt * 2 + 0] & pbits[b * 64 + kt * 2 + 0];
  r.y = mbits[q * 64 + kt * 2 + 1] & pbits[b * 64 + kt * 2 + 1];
  mbt[idx] = r;
}

// ---------------- fp32 -> bf16 converts ----------------
__global__ __launch_bounds__(256)
void cvt_act(const float* __restrict__ q, const float* __restrict__ k,
             const float* __restrict__ v, bf16* __restrict__ out) {
  const float* src = blockIdx.z == 0 ? q : (blockIdx.z == 1 ? k : v);
  size_t i = ((size_t)blockIdx.x * 256 + threadIdx.x) * 8;
  float4 a = *(const float4*)(src + i);
  float4 b = *(const float4*)(src + i + 4);
  bf16x8 o;
  o[0] = (bf16)a.x; o[1] = (bf16)a.y; o[2] = (bf16)a.z; o[3] = (bf16)a.w;
  o[4] = (bf16)b.x; o[5] = (bf16)b.y; o[6] = (bf16)b.z; o[7] = (bf16)b.w;
  *(bf16x8*)(out + (size_t)blockIdx.z * (8192ull * 1024ull) + i) = o;
}

__global__ __launch_bounds__(256)
void cvt_w(const float* __restrict__ w0, const float* __restrict__ w1,
           const float* __restrict__ w2, const float* __restrict__ w3,
           bf16* __restrict__ out, float sq, float sk) {
  int z = blockIdx.z;
  const float* src = z == 0 ? w0 : (z == 1 ? w1 : (z == 2 ? w2 : w3));
  float s = (z == 0) ? sq : ((z == 1) ? sk : 1.0f);
  size_t i = ((size_t)blockIdx.x * 256 + threadIdx.x) * 8;
  float4 a = *(const float4*)(src + i);
  float4 b = *(const float4*)(src + i + 4);
  bf16x8 o;
  o[0] = (bf16)(a.x * s); o[1] = (bf16)(a.y * s); o[2] = (bf16)(a.z * s); o[3] = (bf16)(a.w * s);
  o[4] = (bf16)(b.x * s); o[5] = (bf16)(b.y * s); o[6] = (bf16)(b.z * s); o[7] = (bf16)(b.w * s);
  *(bf16x8*)(out + (size_t)z * (1024ull * 1024ull) + i) = o;
}

// ---------------- GEMM: C = A @ W^T, XCD-chunked grid; z==2 writes V transposed ----------------
// grid.x = 512 flat. XCD k (= id&7 under round-robin) owns row panels [k*8,(k+1)*8) x all cols.
struct GA { const bf16* A; const bf16* W; void* O; };

template<bool OUT_F32>
__global__ __launch_bounds__(256, 4)
void gemm_bf(GA g0, GA g1, GA g2) {
  GA g = (blockIdx.z == 0) ? g0 : ((blockIdx.z == 1) ? g1 : g2);
  const int id = blockIdx.x;
  const int brow = ((id & 7) * 8 + (id >> 6)) * 128;
  const int bcol = ((id >> 3) & 7) * 128;
  const int tid = threadIdx.x;
  const int l = tid & 63, wv = tid >> 6;
  const int lg = l >> 4, lr = l & 15;
  const int wr = wv >> 1, wc = wv & 1;
  const int sr = l >> 3, sc8 = l & 7;

  __shared__ bf16 Ls[2][128 * 64];   // As | Bs (contiguous for transpose reuse)
  bf16* As = Ls[0];
  bf16* Bs = Ls[1];

  f32x4 acc[4][4] = {};

  const bf16* Ab = g.A + (size_t)(brow + wv * 32 + sr) * E_ + (size_t)(sc8 ^ sr) * 8;
  const bf16* Bb = g.W + (size_t)(bcol + wv * 32 + sr) * E_ + (size_t)(sc8 ^ sr) * 8;
  bf16* la = As + (wv * 32) * 64;
  bf16* lb = Bs + (wv * 32) * 64;

  for (int kt = 0; kt < E_ / 64; ++kt) {
    __syncthreads();
    const bf16* a = Ab + kt * 64;
    const bf16* b = Bb + kt * 64;
#pragma unroll
    for (int i = 0; i < 4; ++i) {
      gl_lds16(a + (size_t)i * 8 * E_, la + i * 8 * 64);
      gl_lds16(b + (size_t)i * 8 * E_, lb + i * 8 * 64);
    }
    __syncthreads();
#pragma unroll
    for (int kk = 0; kk < 2; ++kk) {
      bf16x8 af[4], bfr[4];
#pragma unroll
      for (int ms = 0; ms < 4; ++ms) {
        int row = wr * 64 + ms * 16 + lr;
        af[ms] = *(const bf16x8*)&As[sw(row, row * 64 + kk * 32 + lg * 8)];
      }
#pragma unroll
      for (int ns = 0; ns < 4; ++ns) {
        int row = wc * 64 + ns * 16 + lr;
        bfr[ns] = *(const bf16x8*)&Bs[sw(row, row * 64 + kk * 32 + lg * 8)];
      }
#pragma unroll
      for (int ms = 0; ms < 4; ++ms)
#pragma unroll
        for (int ns = 0; ns < 4; ++ns)
          acc[ms][ns] = mfma16(af[ms], bfr[ns], acc[ms][ns]);
    }
  }

  if (!OUT_F32 && blockIdx.z == 2) {
    // ---- V epilogue: transpose 128x128 tile via LDS -> Vt[bh][d][s] ----
    bf16* T = &Ls[0][0];               // 128 x 128 bf16 = 32 KB
    __syncthreads();                   // done reading As/Bs
#pragma unroll
    for (int ms = 0; ms < 4; ++ms) {
#pragma unroll
      for (int ns = 0; ns < 4; ++ns) {
        int col = wc * 64 + ns * 16 + lr;                 // E-dim (d)
        int rowb = wr * 64 + ms * 16 + lg * 4;            // s-dim
        bf16x4 hv;
#pragma unroll
        for (int r = 0; r < 4; ++r) hv[r] = (bf16)acc[ms][ns][r];
        *(bf16x4*)&T[col * 128 + (rowb ^ ((col & 7) << 3))] = hv;
      }
    }
    __syncthreads();
    int chunk = tid & 15, dl0 = tid >> 4;
#pragma unroll
    for (int pass = 0; pass < 8; ++pass) {
      int dl = pass * 16 + dl0;
      bf16x8 v = *(const bf16x8*)&T[dl * 128 + ((chunk * 8) ^ ((dl & 7) << 3))];
      int colg = bcol + dl;
      int bh2 = (brow >> 11) * 16 + (colg >> 6);
      int d = colg & 63;
      int s0 = (brow & 2047) + chunk * 8;
      *(bf16x8*)((bf16*)g.O + ((size_t)bh2 * 64 + d) * (size_t)S_ + s0) = v;
    }
    return;
  }

#pragma unroll
  for (int ms = 0; ms < 4; ++ms) {
#pragma unroll
    for (int ns = 0; ns < 4; ++ns) {
#pragma unroll
      for (int r = 0; r < 4; ++r) {
        int row = brow + wr * 64 + ms * 16 + lg * 4 + r;
        int col = bcol + wc * 64 + ns * 16 + lr;
        if constexpr (OUT_F32) ((float*)g.O)[(size_t)row * E_ + col] = acc[ms][ns][r];
        else                   ((bf16*)g.O)[(size_t)row * E_ + col] = (bf16)acc[ms][ns][r];
      }
    }
  }
}

// ---------------- flash attention: 32q/wave, QBLK=128, grid 1024 ----------------
// grid(1024): raw -> xcd=raw&7; bh = xcd*8 + (slot>>4); qblk = slot&15
__global__ __launch_bounds__(256, 4)
void attn_kernel(const bf16* __restrict__ Q, const bf16* __restrict__ K,
                 const bf16* __restrict__ Vt, const uint2* __restrict__ mbt,
                 bf16* __restrict__ alpha) {
  const int raw = blockIdx.x;
  const int xcd = raw & 7, slot = raw >> 3;
  const int bh = xcd * 8 + (slot >> 4), qblk = slot & 15;
  const int b = bh >> 4, h = bh & 15;
  const int tid = threadIdx.x, wv = tid >> 6, l = tid & 63;
  const int ln = l & 31, hi = l >> 5;
  const int qw = qblk * 128 + wv * 32;
  const int sr = l >> 3, sc8 = l & 7;
  const int g = (ln & 7) ^ (ln >> 3);      // read-side row-hash

  __shared__ bf16 Ks[2][64 * 64];          // [k][d], swizzled chunks
  __shared__ bf16 Vs[2][64 * 64];          // [d][k], swizzled chunks

  // Q fragments: qreg[dc] = Q[qw+ln][dc*16+hi*8 ..+8]
  bf16x8 qreg[4];
#pragma unroll
  for (int dc = 0; dc < 4; ++dc)
    qreg[dc] = *(const bf16x8*)(Q + (size_t)(b * S_ + qw + ln) * E_ + h * 64 + dc * 16 + hi * 8);

  bf16x8 ones;
#pragma unroll
  for (int j = 0; j < 8; ++j) ones[j] = (bf16)1.0f;

  f32x16 o[2] = {};                        // o[dt]
  f32x16 lacc = {};                        // row-sums of P

  const bf16* Kb = K + (size_t)b * S_ * E_ + (size_t)h * 64;
  const bf16* Vb = Vt + (size_t)bh * 64 * S_;
  const uint2* mrow = mbt + ((size_t)b << 16) + qw + ln;   // [kt<<11] indexed

  auto stage = [&](int buf, int kt) {
#pragma unroll
    for (int op = 0; op < 2; ++op) {
      int rb = wv * 16 + op * 8;
      int cK = (sc8 ^ sr ^ ((rb >> 3) & 7)) * 8;
      gl_lds16(Kb + (size_t)(kt * 64 + rb + sr) * E_ + cK, Ks[buf] + rb * 64);
      gl_lds16(Vb + (size_t)(rb + sr) * S_ + kt * 64 + cK, Vs[buf] + rb * 64);
    }
  };

  stage(0, 0);
  __syncthreads();

  for (int kt = 0; kt < S_ / 64; ++kt) {
    const int cur = kt & 1;
    if (kt + 1 < S_ / 64) stage(cur ^ 1, kt + 1);

    // ---- QK^T: sc[ct] = S^T[k = kt*64+ct*32+crow][q = qw+ln] ----
    f32x16 sc[2] = {};
    __builtin_amdgcn_s_setprio(1);
#pragma unroll
    for (int ct = 0; ct < 2; ++ct) {
#pragma unroll
      for (int dc = 0; dc < 4; ++dc) {
        int row = ct * 32 + ln;
        int c = (dc * 2 + hi) ^ g ^ (ct * 4);
        bf16x8 kf = *(const bf16x8*)&Ks[cur][row * 64 + c * 8];
        sc[ct] = mfma32(kf, qreg[dc], sc[ct]);
      }
    }
    __builtin_amdgcn_s_setprio(0);

    // ---- mask: one coalesced uint2, pre-ANDed with padding ----
    uint2 mv = mrow[kt << 11];
    uint32_t mq[2];
    mq[0] = mv.x >> (hi * 4);
    mq[1] = mv.y >> (hi * 4);

    // ---- p = exp2(s), masked via sbfe+and; pack to bf16 ----
    uint32_t up[16];
#pragma unroll
    for (int ct = 0; ct < 2; ++ct) {
      float p[16];
#pragma unroll
      for (int r = 0; r < 16; ++r) {
        const int rel = (r & 3) + 8 * (r >> 2);
        float pe = __builtin_amdgcn_exp2f(sc[ct][r]);
        uint32_t keep = (uint32_t)__builtin_amdgcn_sbfe(mq[ct], rel, 1);
        p[r] = __builtin_bit_cast(float, __builtin_bit_cast(uint32_t, pe) & keep);
      }
#pragma unroll
      for (int j = 0; j < 8; ++j)
        up[ct * 8 + j] = cvtpk(p[2 * j], p[2 * j + 1]);
    }

    // ---- PV + l-sum via permlane32_swap fragments ----
#pragma unroll
    for (int kc = 0; kc < 4; ++kc) {
      const int ct = kc >> 1, base = ct * 8 + (kc & 1) * 4;
      plswap(up[base + 0], up[base + 2]);
      plswap(up[base + 1], up[base + 3]);
      u32x4 w = {up[base + 0], up[base + 1], up[base + 2], up[base + 3]};
      bf16x8 pf = __builtin_bit_cast(bf16x8, w);
      __builtin_amdgcn_s_setprio(1);
#pragma unroll
      for (int dt = 0; dt < 2; ++dt) {
        int row = dt * 32 + ln;
        int c = (kc * 2 + hi) ^ g ^ (dt * 4);
        bf16x8 vf = *(const bf16x8*)&Vs[cur][row * 64 + c * 8];
        o[dt] = mfma32(vf, pf, o[dt]);
      }
      lacc = mfma32(ones, pf, lacc);
      __builtin_amdgcn_s_setprio(0);
    }
    __syncthreads();
  }

  // ---- epilogue: alpha = o / l ----
  float inv = 1.0f / lacc[0];
  size_t qoff = (size_t)(b * S_ + qw + ln) * E_ + h * 64;
#pragma unroll
  for (int dt = 0; dt < 2; ++dt) {
#pragma unroll
    for (int rg = 0; rg < 4; ++rg) {
      bf16x4 ov;
#pragma unroll
      for (int j = 0; j < 4; ++j) ov[j] = (bf16)(o[dt][rg * 4 + j] * inv);
      *(bf16x4*)(alpha + qoff + dt * 32 + rg * 8 + hi * 4) = ov;
    }
  }
}

// ---------------- launch ----------------
extern "C" void kernel_launch(void* const* d_in, const int* in_sizes, int n_in,
                              void* d_out, int out_size, void* d_ws, size_t ws_size,
                              hipStream_t stream) {
  const float* query = (const float*)d_in[0];
  const float* key_t = (const float*)d_in[1];
  const float* value = (const float*)d_in[2];
  const int*   mask  = (const int*)d_in[3];
  const int*   pad   = (const int*)d_in[4];
  const float* Wq    = (const float*)d_in[5];
  const float* Wk    = (const float*)d_in[6];
  const float* Wv    = (const float*)d_in[7];
  const float* Wo    = (const float*)d_in[8];

  char* ws = (char*)d_ws;
  bf16* Abuf  = (bf16*)ws;                             // 48M activations (bf16)
  bf16* alpha = (bf16*)(ws + ((size_t)16 << 20));      // reuses Abuf after QKV gemm
  bf16* Wb    = (bf16*)(ws + ((size_t)48 << 20));      // 8M weights
  bf16* QKV   = (bf16*)(ws + ((size_t)56 << 20));      // Q, K at +0, +16M; Vt at +32M
  uint32_t* mbits = (uint32_t*)(ws + ((size_t)104 << 20));
  uint32_t* pbits = mbits + (size_t)S_ * 64;           // +512KB
  uint2*    mbt   = (uint2*)(ws + ((size_t)105 << 20));// 2MB: [b][kt][q]

  const size_t AM = 8192ull * 1024ull;
  const size_t WM = 1024ull * 1024ull;
  bf16* Vt = QKV + 2 * AM;                             // V written transposed here

  pack_mask_kernel<<<512, 256, 0, stream>>>(mask, mbits);
  pack_pad_kernel<<<1, 256, 0, stream>>>(pad, pbits);
  expand_mask<<<1024, 256, 0, stream>>>(mbits, pbits, mbt);

  cvt_act<<<dim3(4096, 1, 3), 256, 0, stream>>>(query, key_t, value, Abuf);
  const float qscale = 0.17677669529663687f;           // 1024^-0.25
  const float log2e  = 1.4426950408889634f;
  cvt_w<<<dim3(512, 1, 4), 256, 0, stream>>>(Wq, Wk, Wv, Wo, Wb, qscale * log2e, qscale);

  GA gq{Abuf,          Wb,          QKV};
  GA gk{Abuf + AM,     Wb + WM,     QKV + AM};
  GA gv{Abuf + 2 * AM, Wb + 2 * WM, Vt};
  gemm_bf<false><<<dim3(512, 1, 3), 256, 0, stream>>>(gq, gk, gv);

  attn_kernel<<<1024, 256, 0, stream>>>(QKV, QKV + AM, Vt, mbt, alpha);

  GA go{alpha, Wb + 3 * WM, d_out};
  gemm_bf<true><<<dim3(512, 1, 1), 256, 0, stream>>>(go, go, go);
}